// Round 5
// baseline (680.207 us; speedup 1.0000x reference)
//
#include <hip/hip_runtime.h>

constexpr int Hh = 160, Ww = 160, Bb = 8, Cc = 256, ICn = 32;
constexpr int HWn = Hh * Ww;                 // 25600
constexpr float EPSf = 1e-5f;

// ws float offsets
constexpr int P_WQH  = 0;        // ushort[96][256] qkv weight hi
constexpr int P_WQL  = 12288;    // ushort[96][256] qkv weight lo
constexpr int P_QKVB = 24576;    // [96]
constexpr int P_QKVA = 24672;    // [96]
constexpr int P_DW   = 24768;    // [3][32][3][3][32]
constexpr int P_DB   = 52416;    // [3][32]
constexpr int P_OWB  = 52512;    // ushort[256][96] out weight bf16
constexpr int P_OB   = 77088;    // [256]
constexpr int P_OA   = 77344;    // [1]
constexpr int PLANE  = Bb * ICn * HWn;       // 6,553,600
constexpr int OFF_Q  = 77824;
constexpr int OFF_K  = OFF_Q + PLANE;
constexpr int OFF_V  = OFF_Q + 2 * PLANE;
constexpr int OFF_T  = OFF_Q + 3 * PLANE;    // u16 t_frag[3][1280][5120] (bf16, MFMA A-frag image)
constexpr int OFF_CAT= OFF_Q + 6 * PLANE;    // ushort[3*PLANE] (bf16)

typedef unsigned short u16;
typedef short bf16x8 __attribute__((ext_vector_type(8)));
typedef float f32x4  __attribute__((ext_vector_type(4)));

__device__ __forceinline__ unsigned f2b(float x) {
    unsigned u = __float_as_uint(x);
    return (u + 0x7FFFu + ((u >> 16) & 1u)) >> 16;   // RNE f32->bf16
}
__device__ __forceinline__ float b2f(unsigned b) { return __uint_as_float(b << 16); }

// fragment offset (u16 units) for element (ic,h) of a 5120-elem slice:
// f = ic*160+h; h2=f>>5; jc=f&31; slot=(jc>>4)*5+(h2>>5); lane=(jc&15)|(((h2>>3)&3)<<4); v=h2&7
__device__ __forceinline__ int frag_off(int ic, int h) {
    int f = ic * 160 + h;
    int h2 = f >> 5, jc = f & 31;
    return (((jc >> 4) * 5 + (h2 >> 5)) * 64 + ((jc & 15) | (((h2 >> 3) & 3) << 4))) * 8 + (h2 & 7);
}

struct InPtrs { const float* p[40]; };

// ---------------- prep: fold BN into weights/biases ----------------
__global__ void k_prep(InPtrs in, float* __restrict__ ws) {
    int idx = blockIdx.x * 256 + threadIdx.x;
    if (idx < 24576) {
        int oc = idx >> 8, c = idx & 255;
        int z = oc >> 5, o = oc & 31;
        const float* wz = in.p[1 + 6 * z];
        float s = in.p[2 + 6 * z][o] * rsqrtf(in.p[5 + 6 * z][o] + EPSf);
        float wf = wz[o * 256 + c] * s;
        unsigned hi = f2b(wf);
        unsigned lo = f2b(wf - b2f(hi));
        ((u16*)(ws + P_WQH))[oc * 256 + c] = (u16)hi;
        ((u16*)(ws + P_WQL))[oc * 256 + c] = (u16)lo;
    } else if (idx < 24672) {
        int oc = idx - 24576; int z = oc >> 5, o = oc & 31;
        float s = in.p[2 + 6 * z][o] * rsqrtf(in.p[5 + 6 * z][o] + EPSf);
        ws[P_QKVB + oc] = in.p[3 + 6 * z][o] - in.p[4 + 6 * z][o] * s;
    } else if (idx < 24768) {
        int oc = idx - 24672; int z = oc >> 5;
        ws[P_QKVA + oc] = in.p[6 + 6 * z][0];
    } else if (idx < 52416) {
        int j = idx - 24768;
        int d = j / 9216, r2 = j % 9216;
        int oc = r2 & 31; int tmp = r2 >> 5;
        int kx = tmp % 3; tmp /= 3; int ky = tmp % 3; int ic2 = tmp / 3;
        const float* wd = in.p[19 + 5 * d];
        float s = in.p[20 + 5 * d][oc] * rsqrtf(in.p[23 + 5 * d][oc] + EPSf);
        ws[P_DW + j] = wd[((oc * 32 + ic2) * 3 + ky) * 3 + kx] * s;
    } else if (idx < 52512) {
        int j = idx - 52416; int d = j >> 5, oc = j & 31;
        float s = in.p[20 + 5 * d][oc] * rsqrtf(in.p[23 + 5 * d][oc] + EPSf);
        ws[P_DB + j] = in.p[21 + 5 * d][oc] - in.p[22 + 5 * d][oc] * s;
    } else if (idx < 77088) {
        int j2 = idx - 52512; int c = j2 / 96;
        float s = in.p[35][c] * rsqrtf(in.p[38][c] + EPSf);
        ((u16*)(ws + P_OWB))[j2] = (u16)f2b(in.p[34][j2] * s);
    } else if (idx < 77344) {
        int c = idx - 77088;
        float s = in.p[35][c] * rsqrtf(in.p[38][c] + EPSf);
        ws[P_OB + c] = in.p[36][c] - in.p[37][c] * s;
    } else if (idx == 77344) {
        ws[P_OA] = in.p[39][0];
    }
}

// ---------------- q/k/v 1x1 conv: bf16 hi/lo MFMA GEMM M=96,K=256,N=204800 ----------------
__global__ __launch_bounds__(256) void k_qkv(const float* __restrict__ feat,
                                             float* __restrict__ ws) {
    __shared__ u16 BhS[8192];   // 16 slots(ks,nt) x 64 lanes x 8 bf16
    __shared__ u16 BlS[8192];
    const int tid = threadIdx.x;
    const int wv = tid >> 6, l = tid & 63;
    const int g = l >> 4, c15 = l & 15;
    const int n0 = blockIdx.x * 128;
    const int b = n0 / HWn, hw0 = n0 % HWn;
    const float* fbase = feat + (size_t)b * Cc * HWn + hw0;
    const u16* __restrict__ WQH = (const u16*)(ws + P_WQH);
    const u16* __restrict__ WQL = (const u16*)(ws + P_WQL);
    f32x4 acc[6][2];
    f32x4 z4 = {0.f, 0.f, 0.f, 0.f};
#pragma unroll
    for (int mt = 0; mt < 6; mt++) { acc[mt][0] = z4; acc[mt][1] = z4; }

    for (int kc = 0; kc < 4; kc++) {
        __syncthreads();
#pragma unroll
        for (int ss = 0; ss < 4; ss++) {      // 1024 slots
            int s = tid + ss * 256;
            int sl = s & 63, si = s >> 6;     // si = ks*8+nt
            int k0 = kc * 64 + (si >> 3) * 32 + (sl >> 4) * 8;
            int nn = (si & 7) * 16 + (sl & 15);
            const float* gp = fbase + (size_t)k0 * HWn + nn;
            unsigned hb[8], lb[8];
#pragma unroll
            for (int v = 0; v < 8; v++) {
                float x = gp[(size_t)v * HWn];
                hb[v] = f2b(x);
                lb[v] = f2b(x - b2f(hb[v]));
            }
            uint4 hv = {hb[0] | (hb[1] << 16), hb[2] | (hb[3] << 16),
                        hb[4] | (hb[5] << 16), hb[6] | (hb[7] << 16)};
            uint4 lv = {lb[0] | (lb[1] << 16), lb[2] | (lb[3] << 16),
                        lb[4] | (lb[5] << 16), lb[6] | (lb[7] << 16)};
            *(uint4*)(&BhS[(si * 64 + sl) * 8]) = hv;
            *(uint4*)(&BlS[(si * 64 + sl) * 8]) = lv;
        }
        __syncthreads();
#pragma unroll
        for (int ks = 0; ks < 2; ks++) {
            bf16x8 bh[2], bl[2];
#pragma unroll
            for (int ntl = 0; ntl < 2; ntl++) {
                int nt = wv * 2 + ntl;
                bh[ntl] = *(const bf16x8*)(&BhS[((ks * 8 + nt) * 64 + l) * 8]);
                bl[ntl] = *(const bf16x8*)(&BlS[((ks * 8 + nt) * 64 + l) * 8]);
            }
#pragma unroll
            for (int mt = 0; mt < 6; mt++) {
                int arow = (16 * mt + c15) * 256 + kc * 64 + ks * 32 + g * 8;
                bf16x8 ah = *(const bf16x8*)(WQH + arow);
                bf16x8 al = *(const bf16x8*)(WQL + arow);
#pragma unroll
                for (int ntl = 0; ntl < 2; ntl++) {
                    acc[mt][ntl] = __builtin_amdgcn_mfma_f32_16x16x32_bf16(ah, bh[ntl], acc[mt][ntl], 0, 0, 0);
                    acc[mt][ntl] = __builtin_amdgcn_mfma_f32_16x16x32_bf16(ah, bl[ntl], acc[mt][ntl], 0, 0, 0);
                    acc[mt][ntl] = __builtin_amdgcn_mfma_f32_16x16x32_bf16(al, bh[ntl], acc[mt][ntl], 0, 0, 0);
                }
            }
        }
    }
    // epilogue: bias + PReLU, scatter to f32 q/k/v planes (coalesced per oc)
#pragma unroll
    for (int mt = 0; mt < 6; mt++)
#pragma unroll
        for (int ntl = 0; ntl < 2; ntl++) {
            int pos = hw0 + (wv * 2 + ntl) * 16 + c15;
#pragma unroll
            for (int jr = 0; jr < 4; jr++) {
                int oc = 16 * mt + 4 * g + jr;
                float bb = ws[P_QKVB + oc];
                float aa = ws[P_QKVA + oc];
                float y = acc[mt][ntl][jr] + bb;
                y = y >= 0.f ? y : aa * y;
                int z = oc >> 5, o = oc & 31;
                ws[OFF_Q + (size_t)z * PLANE + ((size_t)b * ICn + o) * HWn + pos] = y;
            }
        }
}

// ---------------- dilated 3x3 convs -> bf16 t_frag (MFMA A-fragment image) ----------------
// block: 4 rows x 160 w; 320 threads, vertical pixel pairs (h, h+1) at fixed w.
// 64B output lines (4 h x 8 oc-phases) are filled entirely within one block -> L2 merges.
__global__ __launch_bounds__(320) void k_dconv(float* __restrict__ ws) {
    __shared__ float wsm[9216];      // [ic][9][32]
    const int d = blockIdx.z;
    const int dil = 1 + 2 * d;
    const int b = blockIdx.y;
    const int tid = threadIdx.x;
    for (int i = tid; i < 9216; i += 320) wsm[i] = ws[P_DW + d * 9216 + i];
    __syncthreads();

    const int w = tid % 160;
    const int h = blockIdx.x * 4 + (tid / 160) * 2;   // pixels (h, h+1)
    const float* __restrict__ vbase = ws + OFF_V + (size_t)b * ICn * HWn;

    int wo[3]; bool wvd[3];
    int r0o[3]; bool r0v[3];
    int r1o[3]; bool r1v[3];
#pragma unroll
    for (int t = 0; t < 3; t++) {
        int wp = w + dil * (t - 1);
        wvd[t] = (unsigned)wp < 160u; wo[t] = wp;
        int hh0 = h + dil * (t - 1);
        r0v[t] = (unsigned)hh0 < 160u; r0o[t] = hh0 * Ww;
        int hh1 = h + 1 + dil * (t - 1);
        r1v[t] = (unsigned)hh1 < 160u; r1o[t] = hh1 * Ww;
    }

    float acc[32][2];
#pragma unroll
    for (int o = 0; o < 32; o++) { acc[o][0] = 0.f; acc[o][1] = 0.f; }

    for (int ic = 0; ic < ICn; ic++) {
        const float* vp = vbase + ic * HWn;
        float v0[9], v1[9];
#pragma unroll
        for (int ky = 0; ky < 3; ky++)
#pragma unroll
            for (int kx = 0; kx < 3; kx++) {
                int kk = ky * 3 + kx;
                v0[kk] = (r0v[ky] && wvd[kx]) ? vp[r0o[ky] + wo[kx]] : 0.f;
                v1[kk] = (r1v[ky] && wvd[kx]) ? vp[r1o[ky] + wo[kx]] : 0.f;
            }
        const float* wr = wsm + ic * 288;
#pragma unroll
        for (int k = 0; k < 9; k++) {
            float a0 = v0[k], a1 = v1[k];
#pragma unroll
            for (int oq = 0; oq < 8; oq++) {
                float4 wv = *(const float4*)(wr + k * 32 + 4 * oq);
                acc[4 * oq + 0][0] += a0 * wv.x; acc[4 * oq + 0][1] += a1 * wv.x;
                acc[4 * oq + 1][0] += a0 * wv.y; acc[4 * oq + 1][1] += a1 * wv.y;
                acc[4 * oq + 2][0] += a0 * wv.z; acc[4 * oq + 2][1] += a1 * wv.z;
                acc[4 * oq + 3][0] += a0 * wv.w; acc[4 * oq + 3][1] += a1 * wv.w;
            }
        }
    }
    u16* tf = (u16*)(ws + OFF_T);
    size_t slice = ((size_t)d * (Bb * Ww) + (size_t)b * Ww + w) * 5120;
    const float* bd = ws + P_DB + d * 32;
#pragma unroll
    for (int o = 0; o < 32; o++) {
        float y0 = fmaxf(acc[o][0] + bd[o], 0.f);
        float y1 = fmaxf(acc[o][1] + bd[o], 0.f);
        tf[slice + frag_off(o, h)]     = (u16)f2b(y0);
        tf[slice + frag_off(o, h + 1)] = (u16)f2b(y1);
    }
}

// ---------------- attention: MFMA bf16; t read as fragments directly from global ----------------
__device__ __forceinline__ void stage_qk_hilo(const float* __restrict__ g,
                                              char* hi_buf, char* lo_buf, int tid) {
#pragma unroll
    for (int ss = 0; ss < 2; ss++) {
        int s = tid + ss * 320;          // 640 slots = 10 tiles x 64 lanes
        int l = s & 63, rt = s >> 6;
        int h = 16 * rt + (l & 15);
        int icb = (l >> 4) * 8;
        const float* gp = g + (size_t)icb * HWn + h * Ww;
        unsigned hb[8], lb[8];
#pragma unroll
        for (int v = 0; v < 8; v++) {
            float x = gp[(size_t)v * HWn];
            hb[v] = f2b(x);
            lb[v] = f2b(x - b2f(hb[v]));
        }
        uint4 hv = {hb[0] | (hb[1] << 16), hb[2] | (hb[3] << 16),
                    hb[4] | (hb[5] << 16), hb[6] | (hb[7] << 16)};
        uint4 lv = {lb[0] | (lb[1] << 16), lb[2] | (lb[3] << 16),
                    lb[4] | (lb[5] << 16), lb[6] | (lb[7] << 16)};
        *(uint4*)(hi_buf + s * 16) = hv;
        *(uint4*)(lo_buf + s * 16) = lv;
    }
}

__global__ __launch_bounds__(320) void k_att(float* __restrict__ ws) {
    extern __shared__ char smem[];
    char* q_hi = smem;               // 10240 B each
    char* q_lo = smem + 10240;
    char* k_hi = smem + 20480;
    char* k_lo = smem + 30720;
    char* Sb   = smem;               // 51200 B, reuses q/k region after barrier
    const int tid = threadIdx.x;
    const int bid = blockIdx.x;
    const int r8 = bid & 7, qq = bid >> 3;   // XCD swizzle
    const int b = qq / 20;
    const int w = r8 * 20 + (qq % 20);
    const int bw = b * Ww + w;
    const int wv = tid >> 6;
    const int l  = tid & 63;
    const int g  = l >> 4;
    const int c  = l & 15;

    const float* qg = ws + OFF_Q + (size_t)b * ICn * HWn + w;
    const float* kg = ws + OFF_K + (size_t)b * ICn * HWn + w;
    stage_qk_hilo(qg, q_hi, q_lo, tid);
    stage_qk_hilo(kg, k_hi, k_lo, tid);
    __syncthreads();

    bf16x8 bq[2][2];
#pragma unroll
    for (int ct = 0; ct < 2; ct++) {
        int tau = 2 * wv + ct;
        bq[ct][0] = *(bf16x8*)(q_hi + (tau * 64 + l) * 16);
        bq[ct][1] = *(bf16x8*)(q_lo + (tau * 64 + l) * 16);
    }
    f32x4 acc[10][2];
    f32x4 z4 = {0.f, 0.f, 0.f, 0.f};
#pragma unroll
    for (int rt = 0; rt < 10; rt++) { acc[rt][0] = z4; acc[rt][1] = z4; }
#pragma unroll
    for (int rt = 0; rt < 10; rt++) {
        bf16x8 ah = *(bf16x8*)(k_hi + (rt * 64 + l) * 16);
        bf16x8 al = *(bf16x8*)(k_lo + (rt * 64 + l) * 16);
#pragma unroll
        for (int ct = 0; ct < 2; ct++) {
            acc[rt][ct] = __builtin_amdgcn_mfma_f32_16x16x32_bf16(ah, bq[ct][0], acc[rt][ct], 0, 0, 0);
            acc[rt][ct] = __builtin_amdgcn_mfma_f32_16x16x32_bf16(ah, bq[ct][1], acc[rt][ct], 0, 0, 0);
            acc[rt][ct] = __builtin_amdgcn_mfma_f32_16x16x32_bf16(al, bq[ct][0], acc[rt][ct], 0, 0, 0);
        }
    }
    __syncthreads();   // all q/k reads done; Sb region free

    float mx[2] = {-3.4e38f, -3.4e38f};
#pragma unroll
    for (int rt = 0; rt < 10; rt++)
#pragma unroll
        for (int ct = 0; ct < 2; ct++)
#pragma unroll
            for (int j = 0; j < 4; j++) mx[ct] = fmaxf(mx[ct], acc[rt][ct][j]);
#pragma unroll
    for (int ct = 0; ct < 2; ct++) {
        mx[ct] = fmaxf(mx[ct], __shfl_xor(mx[ct], 16));
        mx[ct] = fmaxf(mx[ct], __shfl_xor(mx[ct], 32));
    }
    float sm[2] = {0.f, 0.f};
#pragma unroll
    for (int rt = 0; rt < 10; rt++)
#pragma unroll
        for (int ct = 0; ct < 2; ct++)
#pragma unroll
            for (int j = 0; j < 4; j++) {
                float e = __expf(acc[rt][ct][j] - mx[ct]);
                acc[rt][ct][j] = e;
                sm[ct] += e;
            }
#pragma unroll
    for (int ct = 0; ct < 2; ct++) {
        sm[ct] += __shfl_xor(sm[ct], 16);
        sm[ct] += __shfl_xor(sm[ct], 32);
    }
    float inv[2] = {1.f / sm[0], 1.f / sm[1]};

#pragma unroll
    for (int rt = 0; rt < 10; rt++) {
#pragma unroll
        for (int ct = 0; ct < 2; ct++) {
            float p0 = acc[rt][ct][0] * inv[ct];
            float p1 = acc[rt][ct][1] * inv[ct];
            float p2 = acc[rt][ct][2] * inv[ct];
            float p3 = acc[rt][ct][3] * inv[ct];
            unsigned d0 = f2b(p0) | (f2b(p1) << 16);
            unsigned d1 = f2b(p2) | (f2b(p3) << 16);
            int Lf = c + 16 * (2 * (rt & 1) + (g >> 1));
            char* dst = Sb + (((wv * 2 + ct) * 5 + (rt >> 1)) * 64 + Lf) * 16 + 8 * (g & 1);
            uint2 dd; dd.x = d0; dd.y = d1;
            *(uint2*)dst = dd;
        }
    }
    __syncthreads();

    const u16* tf = (const u16*)(ws + OFF_T);
    u16* catb = (u16*)(ws + OFF_CAT);
    for (int d = 0; d < 3; d++) {
        const u16* tfd = tf + ((size_t)d * (Bb * Ww) + bw) * 5120;
        f32x4 po[2][2];
        po[0][0] = z4; po[0][1] = z4; po[1][0] = z4; po[1][1] = z4;
#pragma unroll
        for (int ks = 0; ks < 5; ks++) {
            bf16x8 a0 = *(const bf16x8*)(tfd + ((0 * 5 + ks) * 64 + l) * 8);   // coalesced 16B/lane
            bf16x8 a1 = *(const bf16x8*)(tfd + ((1 * 5 + ks) * 64 + l) * 8);
            bf16x8 s0 = *(bf16x8*)(Sb + (((wv * 2 + 0) * 5 + ks) * 64 + l) * 16);
            bf16x8 s1 = *(bf16x8*)(Sb + (((wv * 2 + 1) * 5 + ks) * 64 + l) * 16);
            po[0][0] = __builtin_amdgcn_mfma_f32_16x16x32_bf16(a0, s0, po[0][0], 0, 0, 0);
            po[0][1] = __builtin_amdgcn_mfma_f32_16x16x32_bf16(a0, s1, po[0][1], 0, 0, 0);
            po[1][0] = __builtin_amdgcn_mfma_f32_16x16x32_bf16(a1, s0, po[1][0], 0, 0, 0);
            po[1][1] = __builtin_amdgcn_mfma_f32_16x16x32_bf16(a1, s1, po[1][1], 0, 0, 0);
        }
#pragma unroll
        for (int jt = 0; jt < 2; jt++)
#pragma unroll
            for (int ct = 0; ct < 2; ct++) {
                int h1 = 32 * wv + 16 * ct + c;
                size_t idx = (size_t)d * PLANE + (size_t)bw * 5120 + h1 * 32 + 16 * jt + 4 * g;
                f32x4 v = po[jt][ct];
                uint2 dd;
                dd.x = f2b(v[0]) | (f2b(v[1]) << 16);
                dd.y = f2b(v[2]) | (f2b(v[3]) << 16);
                *(uint2*)(catb + idx) = dd;
            }
    }
}

// ---------------- output 1x1 conv: bf16 MFMA GEMM M=256,K=96,N=204800 ----------------
__global__ __launch_bounds__(256) void k_out(const float* __restrict__ feat,
                                             const float* __restrict__ ws,
                                             float* __restrict__ out) {
    __shared__ u16 Bs[12288];   // 24 slots(ks,nt) x 64 lanes x 8 bf16
    const int tid = threadIdx.x;
    const int wv = tid >> 6, l = tid & 63;
    const int g = l >> 4, c15 = l & 15;
    const int n0 = blockIdx.x * 128;
    const int b = n0 / HWn, hw0 = n0 % HWn;
    const u16* __restrict__ CATb = (const u16*)(ws + OFF_CAT);
    const u16* __restrict__ OWB = (const u16*)(ws + P_OWB);

#pragma unroll
    for (int ss = 0; ss < 6; ss++) {
        int s = tid + ss * 256;
        int sl = s & 63, si = s >> 6;    // si = ks*8+nt, 0..23
        int p = (si & 7) * 16 + (sl & 15);
        int hw = hw0 + p;
        int h = hw / Ww, w2 = hw % Ww;
        int j = (si >> 3) * 32 + (sl >> 4) * 8;
        size_t flat = ((size_t)(b * Ww + w2) * Hh + h) * 96 + j;
        *(uint4*)(&Bs[(si * 64 + sl) * 8]) = *(const uint4*)(CATb + flat);
    }
    bf16x8 af[4][3];
#pragma unroll
    for (int mt = 0; mt < 4; mt++)
#pragma unroll
        for (int ks = 0; ks < 3; ks++)
            af[mt][ks] = *(const bf16x8*)(OWB + (wv * 64 + mt * 16 + c15) * 96 + ks * 32 + g * 8);
    __syncthreads();
    const float alpha = ws[P_OA];

    f32x4 z4 = {0.f, 0.f, 0.f, 0.f};
#pragma unroll
    for (int np = 0; np < 2; np++) {
        f32x4 acc[4][4];
#pragma unroll
        for (int mt = 0; mt < 4; mt++)
#pragma unroll
            for (int ntl = 0; ntl < 4; ntl++) acc[mt][ntl] = z4;
#pragma unroll
        for (int ks = 0; ks < 3; ks++) {
            bf16x8 bf_[4];
#pragma unroll
            for (int ntl = 0; ntl < 4; ntl++)
                bf_[ntl] = *(const bf16x8*)(&Bs[((ks * 8 + np * 4 + ntl) * 64 + l) * 8]);
#pragma unroll
            for (int mt = 0; mt < 4; mt++)
#pragma unroll
                for (int ntl = 0; ntl < 4; ntl++)
                    acc[mt][ntl] = __builtin_amdgcn_mfma_f32_16x16x32_bf16(af[mt][ks], bf_[ntl], acc[mt][ntl], 0, 0, 0);
        }
#pragma unroll
        for (int mt = 0; mt < 4; mt++)
#pragma unroll
            for (int ntl = 0; ntl < 4; ntl++) {
                int p = (np * 4 + ntl) * 16 + c15;
#pragma unroll
                for (int jr = 0; jr < 4; jr++) {
                    int cch = wv * 64 + mt * 16 + 4 * g + jr;
                    size_t base = ((size_t)b * Cc + cch) * HWn + hw0 + p;
                    float y = acc[mt][ntl][jr] + ws[P_OB + cch] + feat[base];
                    out[base] = y >= 0.f ? y : alpha * y;
                }
            }
    }
}

extern "C" void kernel_launch(void* const* d_in, const int* in_sizes, int n_in,
                              void* d_out, int out_size, void* d_ws, size_t ws_size,
                              hipStream_t stream) {
    InPtrs ip;
    for (int i = 0; i < 40; i++) ip.p[i] = (const float*)d_in[i];
    float* ws = (float*)d_ws;
    const float* feat = (const float*)d_in[0];
    float* out = (float*)d_out;

    k_prep<<<304, 256, 0, stream>>>(ip, ws);
    k_qkv<<<1600, 256, 0, stream>>>(feat, ws);
    k_dconv<<<dim3(40, 8, 3), 320, 0, stream>>>(ws);
    (void)hipFuncSetAttribute(reinterpret_cast<const void*>(k_att),
                              hipFuncAttributeMaxDynamicSharedMemorySize, 51200);
    k_att<<<1280, 320, 51200, stream>>>(ws);
    k_out<<<1600, 256, 0, stream>>>(feat, ws, out);
}

// Round 6
// 588.993 us; speedup vs baseline: 1.1549x; 1.1549x over previous
//
#include <hip/hip_runtime.h>

constexpr int Hh = 160, Ww = 160, Bb = 8, Cc = 256, ICn = 32;
constexpr int HWn = Hh * Ww;                 // 25600
constexpr float EPSf = 1e-5f;

// ws float offsets
constexpr int P_WQH  = 0;        // ushort[96][256] qkv weight hi
constexpr int P_WQL  = 12288;    // ushort[96][256] qkv weight lo
constexpr int P_QKVB = 24576;    // [96]
constexpr int P_QKVA = 24672;    // [96]
constexpr int P_DW   = 24768;    // [3][32][3][3][32]
constexpr int P_DB   = 52416;    // [3][32]
constexpr int P_OWB  = 52512;    // ushort[256][96] out weight bf16
constexpr int P_OB   = 77088;    // [256]
constexpr int P_OA   = 77344;    // [1]
constexpr int PLANE  = Bb * ICn * HWn;       // 6,553,600
constexpr int OFF_Q  = 77824;
constexpr int OFF_K  = OFF_Q + PLANE;
constexpr int OFF_V  = OFF_Q + 2 * PLANE;
constexpr int OFF_T  = OFF_Q + 3 * PLANE;    // u16 t_frag[3][1280][5120] (bf16 MFMA A-frag image)
constexpr int OFF_TPF= OFF_T + (3 * PLANE) / 2;  // u16 tp[3][8][32][25600] planar bf16
constexpr int OFF_CAT= OFF_Q + 6 * PLANE;    // ushort[3*PLANE] (bf16)

typedef unsigned short u16;
typedef short bf16x8 __attribute__((ext_vector_type(8)));
typedef float f32x4  __attribute__((ext_vector_type(4)));

__device__ __forceinline__ unsigned f2b(float x) {
    unsigned u = __float_as_uint(x);
    return (u + 0x7FFFu + ((u >> 16) & 1u)) >> 16;   // RNE f32->bf16
}
__device__ __forceinline__ float b2f(unsigned b) { return __uint_as_float(b << 16); }

struct InPtrs { const float* p[40]; };

// ---------------- prep: fold BN into weights/biases ----------------
__global__ void k_prep(InPtrs in, float* __restrict__ ws) {
    int idx = blockIdx.x * 256 + threadIdx.x;
    if (idx < 24576) {
        int oc = idx >> 8, c = idx & 255;
        int z = oc >> 5, o = oc & 31;
        const float* wz = in.p[1 + 6 * z];
        float s = in.p[2 + 6 * z][o] * rsqrtf(in.p[5 + 6 * z][o] + EPSf);
        float wf = wz[o * 256 + c] * s;
        unsigned hi = f2b(wf);
        unsigned lo = f2b(wf - b2f(hi));
        ((u16*)(ws + P_WQH))[oc * 256 + c] = (u16)hi;
        ((u16*)(ws + P_WQL))[oc * 256 + c] = (u16)lo;
    } else if (idx < 24672) {
        int oc = idx - 24576; int z = oc >> 5, o = oc & 31;
        float s = in.p[2 + 6 * z][o] * rsqrtf(in.p[5 + 6 * z][o] + EPSf);
        ws[P_QKVB + oc] = in.p[3 + 6 * z][o] - in.p[4 + 6 * z][o] * s;
    } else if (idx < 24768) {
        int oc = idx - 24672; int z = oc >> 5;
        ws[P_QKVA + oc] = in.p[6 + 6 * z][0];
    } else if (idx < 52416) {
        int j = idx - 24768;
        int d = j / 9216, r2 = j % 9216;
        int oc = r2 & 31; int tmp = r2 >> 5;
        int kx = tmp % 3; tmp /= 3; int ky = tmp % 3; int ic2 = tmp / 3;
        const float* wd = in.p[19 + 5 * d];
        float s = in.p[20 + 5 * d][oc] * rsqrtf(in.p[23 + 5 * d][oc] + EPSf);
        ws[P_DW + j] = wd[((oc * 32 + ic2) * 3 + ky) * 3 + kx] * s;
    } else if (idx < 52512) {
        int j = idx - 52416; int d = j >> 5, oc = j & 31;
        float s = in.p[20 + 5 * d][oc] * rsqrtf(in.p[23 + 5 * d][oc] + EPSf);
        ws[P_DB + j] = in.p[21 + 5 * d][oc] - in.p[22 + 5 * d][oc] * s;
    } else if (idx < 77088) {
        int j2 = idx - 52512; int c = j2 / 96;
        float s = in.p[35][c] * rsqrtf(in.p[38][c] + EPSf);
        ((u16*)(ws + P_OWB))[j2] = (u16)f2b(in.p[34][j2] * s);
    } else if (idx < 77344) {
        int c = idx - 77088;
        float s = in.p[35][c] * rsqrtf(in.p[38][c] + EPSf);
        ws[P_OB + c] = in.p[36][c] - in.p[37][c] * s;
    } else if (idx == 77344) {
        ws[P_OA] = in.p[39][0];
    }
}

// ---------------- q/k/v 1x1 conv: bf16 hi/lo MFMA GEMM M=96,K=256,N=204800 ----------------
__global__ __launch_bounds__(256) void k_qkv(const float* __restrict__ feat,
                                             float* __restrict__ ws) {
    __shared__ u16 BhS[8192];   // 16 slots(ks,nt) x 64 lanes x 8 bf16
    __shared__ u16 BlS[8192];
    const int tid = threadIdx.x;
    const int wv = tid >> 6, l = tid & 63;
    const int g = l >> 4, c15 = l & 15;
    const int n0 = blockIdx.x * 128;
    const int b = n0 / HWn, hw0 = n0 % HWn;
    const float* fbase = feat + (size_t)b * Cc * HWn + hw0;
    const u16* __restrict__ WQH = (const u16*)(ws + P_WQH);
    const u16* __restrict__ WQL = (const u16*)(ws + P_WQL);
    f32x4 acc[6][2];
    f32x4 z4 = {0.f, 0.f, 0.f, 0.f};
#pragma unroll
    for (int mt = 0; mt < 6; mt++) { acc[mt][0] = z4; acc[mt][1] = z4; }

    for (int kc = 0; kc < 4; kc++) {
        __syncthreads();
#pragma unroll
        for (int ss = 0; ss < 4; ss++) {      // 1024 slots
            int s = tid + ss * 256;
            int sl = s & 63, si = s >> 6;     // si = ks*8+nt
            int k0 = kc * 64 + (si >> 3) * 32 + (sl >> 4) * 8;
            int nn = (si & 7) * 16 + (sl & 15);
            const float* gp = fbase + (size_t)k0 * HWn + nn;
            unsigned hb[8], lb[8];
#pragma unroll
            for (int v = 0; v < 8; v++) {
                float x = gp[(size_t)v * HWn];
                hb[v] = f2b(x);
                lb[v] = f2b(x - b2f(hb[v]));
            }
            uint4 hv = {hb[0] | (hb[1] << 16), hb[2] | (hb[3] << 16),
                        hb[4] | (hb[5] << 16), hb[6] | (hb[7] << 16)};
            uint4 lv = {lb[0] | (lb[1] << 16), lb[2] | (lb[3] << 16),
                        lb[4] | (lb[5] << 16), lb[6] | (lb[7] << 16)};
            *(uint4*)(&BhS[(si * 64 + sl) * 8]) = hv;
            *(uint4*)(&BlS[(si * 64 + sl) * 8]) = lv;
        }
        __syncthreads();
#pragma unroll
        for (int ks = 0; ks < 2; ks++) {
            bf16x8 bh[2], bl[2];
#pragma unroll
            for (int ntl = 0; ntl < 2; ntl++) {
                int nt = wv * 2 + ntl;
                bh[ntl] = *(const bf16x8*)(&BhS[((ks * 8 + nt) * 64 + l) * 8]);
                bl[ntl] = *(const bf16x8*)(&BlS[((ks * 8 + nt) * 64 + l) * 8]);
            }
#pragma unroll
            for (int mt = 0; mt < 6; mt++) {
                int arow = (16 * mt + c15) * 256 + kc * 64 + ks * 32 + g * 8;
                bf16x8 ah = *(const bf16x8*)(WQH + arow);
                bf16x8 al = *(const bf16x8*)(WQL + arow);
#pragma unroll
                for (int ntl = 0; ntl < 2; ntl++) {
                    acc[mt][ntl] = __builtin_amdgcn_mfma_f32_16x16x32_bf16(ah, bh[ntl], acc[mt][ntl], 0, 0, 0);
                    acc[mt][ntl] = __builtin_amdgcn_mfma_f32_16x16x32_bf16(ah, bl[ntl], acc[mt][ntl], 0, 0, 0);
                    acc[mt][ntl] = __builtin_amdgcn_mfma_f32_16x16x32_bf16(al, bh[ntl], acc[mt][ntl], 0, 0, 0);
                }
            }
        }
    }
    // epilogue: bias + PReLU, scatter to f32 q/k/v planes (coalesced per oc)
#pragma unroll
    for (int mt = 0; mt < 6; mt++)
#pragma unroll
        for (int ntl = 0; ntl < 2; ntl++) {
            int pos = hw0 + (wv * 2 + ntl) * 16 + c15;
#pragma unroll
            for (int jr = 0; jr < 4; jr++) {
                int oc = 16 * mt + 4 * g + jr;
                float bb = ws[P_QKVB + oc];
                float aa = ws[P_QKVA + oc];
                float y = acc[mt][ntl][jr] + bb;
                y = y >= 0.f ? y : aa * y;
                int z = oc >> 5, o = oc & 31;
                ws[OFF_Q + (size_t)z * PLANE + ((size_t)b * ICn + o) * HWn + pos] = y;
            }
        }
}

// ---------------- dilated 3x3 convs: horizontal pixel pairs, packed-bf16 planar stores ----------------
__global__ __launch_bounds__(256) void k_dconv(float* __restrict__ ws) {
    __shared__ float wsm[9216];      // [ic][9][32]
    const int d = blockIdx.y;
    const int dil = 1 + 2 * d;
    const int tid = threadIdx.x;
#pragma unroll
    for (int i = 0; i < 36; i++) wsm[tid + i * 256] = ws[P_DW + d * 9216 + tid + i * 256];
    __syncthreads();

    const int pix0 = blockIdx.x * 512 + tid * 2;
    const int b = pix0 / HWn;
    const int hw = pix0 % HWn;
    const int h = hw / Ww, w = hw % Ww;   // w even, w+1 same row
    const float* __restrict__ vbase = ws + OFF_V + (size_t)b * ICn * HWn;

    int hoff[3]; bool hv[3];
    int wo0[3]; bool wv0[3], wv1[3];
#pragma unroll
    for (int t = 0; t < 3; t++) {
        int hh = h + dil * (t - 1);
        hv[t] = (unsigned)hh < 160u; hoff[t] = hh * Ww;
        int wp = w + dil * (t - 1);
        wv0[t] = (unsigned)wp < 160u; wv1[t] = (unsigned)(wp + 1) < 160u; wo0[t] = wp;
    }

    float acc[32][2];
#pragma unroll
    for (int o = 0; o < 32; o++) { acc[o][0] = 0.f; acc[o][1] = 0.f; }

    for (int ic = 0; ic < ICn; ic++) {
        const float* vp = vbase + ic * HWn;
        float v0[9], v1[9];
#pragma unroll
        for (int ky = 0; ky < 3; ky++)
#pragma unroll
            for (int kx = 0; kx < 3; kx++) {
                int kk = ky * 3 + kx;
                v0[kk] = (hv[ky] && wv0[kx]) ? vp[hoff[ky] + wo0[kx]] : 0.f;
                v1[kk] = (hv[ky] && wv1[kx]) ? vp[hoff[ky] + wo0[kx] + 1] : 0.f;
            }
        const float* wr = wsm + ic * 288;
#pragma unroll
        for (int k = 0; k < 9; k++) {
            float a0 = v0[k], a1 = v1[k];
#pragma unroll
            for (int oq = 0; oq < 8; oq++) {
                float4 wv = *(const float4*)(wr + k * 32 + 4 * oq);
                acc[4 * oq + 0][0] += a0 * wv.x; acc[4 * oq + 0][1] += a1 * wv.x;
                acc[4 * oq + 1][0] += a0 * wv.y; acc[4 * oq + 1][1] += a1 * wv.y;
                acc[4 * oq + 2][0] += a0 * wv.z; acc[4 * oq + 2][1] += a1 * wv.z;
                acc[4 * oq + 3][0] += a0 * wv.w; acc[4 * oq + 3][1] += a1 * wv.w;
            }
        }
    }
    u16* tp = (u16*)(ws + OFF_TPF) + ((size_t)(d * Bb + b) * ICn) * HWn + hw;
    const float* bd = ws + P_DB + d * 32;
#pragma unroll
    for (int o = 0; o < 32; o++) {
        float y0 = fmaxf(acc[o][0] + bd[o], 0.f);
        float y1 = fmaxf(acc[o][1] + bd[o], 0.f);
        *(unsigned*)(tp + (size_t)o * HWn) = f2b(y0) | (f2b(y1) << 16);
    }
}

// ---------------- t re-layout: planar bf16 -> MFMA A-frag image ----------------
// block = (wq, b, d): 4 w-slices; LDS linear stage, frag-gather pack, coalesced stores.
__global__ __launch_bounds__(256) void k_tfrag(float* __restrict__ ws) {
    __shared__ u16 fr[4][5120];
    const int tid = threadIdx.x;
    const int wq = blockIdx.x;      // 0..39
    const int b  = blockIdx.y;      // 0..7
    const int d  = blockIdx.z;      // 0..2
    const int w0 = wq * 4;
    const u16* __restrict__ tp = (const u16*)(ws + OFF_TPF) + (size_t)(d * Bb + b) * ICn * HWn;
    for (int i = tid; i < 5120; i += 256) {
        int ic = i / 160, h = i % 160;
        uint2 v = *(const uint2*)(tp + (size_t)ic * HWn + h * Ww + w0);
        fr[0][i] = (u16)(v.x & 0xFFFFu);
        fr[1][i] = (u16)(v.x >> 16);
        fr[2][i] = (u16)(v.y & 0xFFFFu);
        fr[3][i] = (u16)(v.y >> 16);
    }
    __syncthreads();
    u16* __restrict__ tf = (u16*)(ws + OFF_T);
#pragma unroll
    for (int it = 0; it < 10; it++) {
        int W = tid + it * 256;          // 0..2559
        int s = W / 640, word = W % 640;
        int slot = word >> 6, lane = word & 63;
        int jc = (lane & 15) | ((slot / 5) << 4);
        int h2b = ((slot % 5) << 5) | (((lane >> 4) & 3) << 3);
        unsigned r[4];
#pragma unroll
        for (int p = 0; p < 4; p++) {
            int f0 = (h2b + 2 * p) * 32 + jc;
            unsigned lo = fr[s][f0];
            unsigned hi = fr[s][f0 + 32];
            r[p] = lo | (hi << 16);
        }
        uint4 o4 = {r[0], r[1], r[2], r[3]};
        *(uint4*)(tf + ((size_t)d * 1280 + b * 160 + w0 + s) * 5120 + word * 8) = o4;
    }
}

// ---------------- attention: MFMA bf16; t read as fragments directly from global ----------------
__device__ __forceinline__ void stage_qk_hilo(const float* __restrict__ g,
                                              char* hi_buf, char* lo_buf, int tid) {
#pragma unroll
    for (int ss = 0; ss < 2; ss++) {
        int s = tid + ss * 320;          // 640 slots = 10 tiles x 64 lanes
        int l = s & 63, rt = s >> 6;
        int h = 16 * rt + (l & 15);
        int icb = (l >> 4) * 8;
        const float* gp = g + (size_t)icb * HWn + h * Ww;
        unsigned hb[8], lb[8];
#pragma unroll
        for (int v = 0; v < 8; v++) {
            float x = gp[(size_t)v * HWn];
            hb[v] = f2b(x);
            lb[v] = f2b(x - b2f(hb[v]));
        }
        uint4 hv = {hb[0] | (hb[1] << 16), hb[2] | (hb[3] << 16),
                    hb[4] | (hb[5] << 16), hb[6] | (hb[7] << 16)};
        uint4 lv = {lb[0] | (lb[1] << 16), lb[2] | (lb[3] << 16),
                    lb[4] | (lb[5] << 16), lb[6] | (lb[7] << 16)};
        *(uint4*)(hi_buf + s * 16) = hv;
        *(uint4*)(lo_buf + s * 16) = lv;
    }
}

__global__ __launch_bounds__(320) void k_att(float* __restrict__ ws) {
    extern __shared__ char smem[];
    char* q_hi = smem;               // 10240 B each
    char* q_lo = smem + 10240;
    char* k_hi = smem + 20480;
    char* k_lo = smem + 30720;
    char* Sb   = smem;               // 51200 B, reuses q/k region after barrier
    const int tid = threadIdx.x;
    const int bid = blockIdx.x;
    const int r8 = bid & 7, qq = bid >> 3;   // XCD swizzle
    const int b = qq / 20;
    const int w = r8 * 20 + (qq % 20);
    const int bw = b * Ww + w;
    const int wv = tid >> 6;
    const int l  = tid & 63;
    const int g  = l >> 4;
    const int c  = l & 15;

    const float* qg = ws + OFF_Q + (size_t)b * ICn * HWn + w;
    const float* kg = ws + OFF_K + (size_t)b * ICn * HWn + w;
    stage_qk_hilo(qg, q_hi, q_lo, tid);
    stage_qk_hilo(kg, k_hi, k_lo, tid);
    __syncthreads();

    bf16x8 bq[2][2];
#pragma unroll
    for (int ct = 0; ct < 2; ct++) {
        int tau = 2 * wv + ct;
        bq[ct][0] = *(bf16x8*)(q_hi + (tau * 64 + l) * 16);
        bq[ct][1] = *(bf16x8*)(q_lo + (tau * 64 + l) * 16);
    }
    f32x4 acc[10][2];
    f32x4 z4 = {0.f, 0.f, 0.f, 0.f};
#pragma unroll
    for (int rt = 0; rt < 10; rt++) { acc[rt][0] = z4; acc[rt][1] = z4; }
#pragma unroll
    for (int rt = 0; rt < 10; rt++) {
        bf16x8 ah = *(bf16x8*)(k_hi + (rt * 64 + l) * 16);
        bf16x8 al = *(bf16x8*)(k_lo + (rt * 64 + l) * 16);
#pragma unroll
        for (int ct = 0; ct < 2; ct++) {
            acc[rt][ct] = __builtin_amdgcn_mfma_f32_16x16x32_bf16(ah, bq[ct][0], acc[rt][ct], 0, 0, 0);
            acc[rt][ct] = __builtin_amdgcn_mfma_f32_16x16x32_bf16(ah, bq[ct][1], acc[rt][ct], 0, 0, 0);
            acc[rt][ct] = __builtin_amdgcn_mfma_f32_16x16x32_bf16(al, bq[ct][0], acc[rt][ct], 0, 0, 0);
        }
    }
    __syncthreads();   // all q/k reads done; Sb region free

    float mx[2] = {-3.4e38f, -3.4e38f};
#pragma unroll
    for (int rt = 0; rt < 10; rt++)
#pragma unroll
        for (int ct = 0; ct < 2; ct++)
#pragma unroll
            for (int j = 0; j < 4; j++) mx[ct] = fmaxf(mx[ct], acc[rt][ct][j]);
#pragma unroll
    for (int ct = 0; ct < 2; ct++) {
        mx[ct] = fmaxf(mx[ct], __shfl_xor(mx[ct], 16));
        mx[ct] = fmaxf(mx[ct], __shfl_xor(mx[ct], 32));
    }
    float sm[2] = {0.f, 0.f};
#pragma unroll
    for (int rt = 0; rt < 10; rt++)
#pragma unroll
        for (int ct = 0; ct < 2; ct++)
#pragma unroll
            for (int j = 0; j < 4; j++) {
                float e = __expf(acc[rt][ct][j] - mx[ct]);
                acc[rt][ct][j] = e;
                sm[ct] += e;
            }
#pragma unroll
    for (int ct = 0; ct < 2; ct++) {
        sm[ct] += __shfl_xor(sm[ct], 16);
        sm[ct] += __shfl_xor(sm[ct], 32);
    }
    float inv[2] = {1.f / sm[0], 1.f / sm[1]};

#pragma unroll
    for (int rt = 0; rt < 10; rt++) {
#pragma unroll
        for (int ct = 0; ct < 2; ct++) {
            float p0 = acc[rt][ct][0] * inv[ct];
            float p1 = acc[rt][ct][1] * inv[ct];
            float p2 = acc[rt][ct][2] * inv[ct];
            float p3 = acc[rt][ct][3] * inv[ct];
            unsigned d0 = f2b(p0) | (f2b(p1) << 16);
            unsigned d1 = f2b(p2) | (f2b(p3) << 16);
            int Lf = c + 16 * (2 * (rt & 1) + (g >> 1));
            char* dst = Sb + (((wv * 2 + ct) * 5 + (rt >> 1)) * 64 + Lf) * 16 + 8 * (g & 1);
            uint2 dd; dd.x = d0; dd.y = d1;
            *(uint2*)dst = dd;
        }
    }
    __syncthreads();

    const u16* tf = (const u16*)(ws + OFF_T);
    u16* catb = (u16*)(ws + OFF_CAT);
    for (int d = 0; d < 3; d++) {
        const u16* tfd = tf + ((size_t)d * (Bb * Ww) + bw) * 5120;
        f32x4 po[2][2];
        po[0][0] = z4; po[0][1] = z4; po[1][0] = z4; po[1][1] = z4;
#pragma unroll
        for (int ks = 0; ks < 5; ks++) {
            bf16x8 a0 = *(const bf16x8*)(tfd + ((0 * 5 + ks) * 64 + l) * 8);   // coalesced 16B/lane
            bf16x8 a1 = *(const bf16x8*)(tfd + ((1 * 5 + ks) * 64 + l) * 8);
            bf16x8 s0 = *(bf16x8*)(Sb + (((wv * 2 + 0) * 5 + ks) * 64 + l) * 16);
            bf16x8 s1 = *(bf16x8*)(Sb + (((wv * 2 + 1) * 5 + ks) * 64 + l) * 16);
            po[0][0] = __builtin_amdgcn_mfma_f32_16x16x32_bf16(a0, s0, po[0][0], 0, 0, 0);
            po[0][1] = __builtin_amdgcn_mfma_f32_16x16x32_bf16(a0, s1, po[0][1], 0, 0, 0);
            po[1][0] = __builtin_amdgcn_mfma_f32_16x16x32_bf16(a1, s0, po[1][0], 0, 0, 0);
            po[1][1] = __builtin_amdgcn_mfma_f32_16x16x32_bf16(a1, s1, po[1][1], 0, 0, 0);
        }
#pragma unroll
        for (int jt = 0; jt < 2; jt++)
#pragma unroll
            for (int ct = 0; ct < 2; ct++) {
                int h1 = 32 * wv + 16 * ct + c;
                size_t idx = (size_t)d * PLANE + (size_t)bw * 5120 + h1 * 32 + 16 * jt + 4 * g;
                f32x4 v = po[jt][ct];
                uint2 dd;
                dd.x = f2b(v[0]) | (f2b(v[1]) << 16);
                dd.y = f2b(v[2]) | (f2b(v[3]) << 16);
                *(uint2*)(catb + idx) = dd;
            }
    }
}

// ---------------- output 1x1 conv: bf16 MFMA GEMM M=256,K=96,N=204800 ----------------
__global__ __launch_bounds__(256) void k_out(const float* __restrict__ feat,
                                             const float* __restrict__ ws,
                                             float* __restrict__ out) {
    __shared__ u16 Bs[12288];   // 24 slots(ks,nt) x 64 lanes x 8 bf16
    const int tid = threadIdx.x;
    const int wv = tid >> 6, l = tid & 63;
    const int g = l >> 4, c15 = l & 15;
    const int n0 = blockIdx.x * 128;
    const int b = n0 / HWn, hw0 = n0 % HWn;
    const u16* __restrict__ CATb = (const u16*)(ws + OFF_CAT);
    const u16* __restrict__ OWB = (const u16*)(ws + P_OWB);

#pragma unroll
    for (int ss = 0; ss < 6; ss++) {
        int s = tid + ss * 256;
        int sl = s & 63, si = s >> 6;    // si = ks*8+nt, 0..23
        int p = (si & 7) * 16 + (sl & 15);
        int hw = hw0 + p;
        int h = hw / Ww, w2 = hw % Ww;
        int j = (si >> 3) * 32 + (sl >> 4) * 8;
        size_t flat = ((size_t)(b * Ww + w2) * Hh + h) * 96 + j;
        *(uint4*)(&Bs[(si * 64 + sl) * 8]) = *(const uint4*)(CATb + flat);
    }
    bf16x8 af[4][3];
#pragma unroll
    for (int mt = 0; mt < 4; mt++)
#pragma unroll
        for (int ks = 0; ks < 3; ks++)
            af[mt][ks] = *(const bf16x8*)(OWB + (wv * 64 + mt * 16 + c15) * 96 + ks * 32 + g * 8);
    __syncthreads();
    const float alpha = ws[P_OA];

    f32x4 z4 = {0.f, 0.f, 0.f, 0.f};
#pragma unroll
    for (int np = 0; np < 2; np++) {
        f32x4 acc[4][4];
#pragma unroll
        for (int mt = 0; mt < 4; mt++)
#pragma unroll
            for (int ntl = 0; ntl < 4; ntl++) acc[mt][ntl] = z4;
#pragma unroll
        for (int ks = 0; ks < 3; ks++) {
            bf16x8 bf_[4];
#pragma unroll
            for (int ntl = 0; ntl < 4; ntl++)
                bf_[ntl] = *(const bf16x8*)(&Bs[((ks * 8 + np * 4 + ntl) * 64 + l) * 8]);
#pragma unroll
            for (int mt = 0; mt < 4; mt++)
#pragma unroll
                for (int ntl = 0; ntl < 4; ntl++)
                    acc[mt][ntl] = __builtin_amdgcn_mfma_f32_16x16x32_bf16(af[mt][ks], bf_[ntl], acc[mt][ntl], 0, 0, 0);
        }
#pragma unroll
        for (int mt = 0; mt < 4; mt++)
#pragma unroll
            for (int ntl = 0; ntl < 4; ntl++) {
                int p = (np * 4 + ntl) * 16 + c15;
#pragma unroll
                for (int jr = 0; jr < 4; jr++) {
                    int cch = wv * 64 + mt * 16 + 4 * g + jr;
                    size_t base = ((size_t)b * Cc + cch) * HWn + hw0 + p;
                    float y = acc[mt][ntl][jr] + ws[P_OB + cch] + feat[base];
                    out[base] = y >= 0.f ? y : alpha * y;
                }
            }
    }
}

extern "C" void kernel_launch(void* const* d_in, const int* in_sizes, int n_in,
                              void* d_out, int out_size, void* d_ws, size_t ws_size,
                              hipStream_t stream) {
    InPtrs ip;
    for (int i = 0; i < 40; i++) ip.p[i] = (const float*)d_in[i];
    float* ws = (float*)d_ws;
    const float* feat = (const float*)d_in[0];
    float* out = (float*)d_out;

    k_prep<<<304, 256, 0, stream>>>(ip, ws);
    k_qkv<<<1600, 256, 0, stream>>>(feat, ws);
    k_dconv<<<dim3(400, 3, 1), 256, 0, stream>>>(ws);
    k_tfrag<<<dim3(40, 8, 3), 256, 0, stream>>>(ws);
    (void)hipFuncSetAttribute(reinterpret_cast<const void*>(k_att),
                              hipFuncAttributeMaxDynamicSharedMemorySize, 51200);
    k_att<<<1280, 320, 51200, stream>>>(ws);
    k_out<<<1600, 256, 0, stream>>>(feat, ws, out);
}

// Round 7
// 468.701 us; speedup vs baseline: 1.4513x; 1.2567x over previous
//
#include <hip/hip_runtime.h>

constexpr int Hh = 160, Ww = 160, Bb = 8, Cc = 256, ICn = 32;
constexpr int HWn = Hh * Ww;                 // 25600
constexpr float EPSf = 1e-5f;

// ws float offsets
constexpr int P_WQH  = 0;        // ushort[96][256] qkv weight hi
constexpr int P_WQL  = 12288;    // ushort[96][256] qkv weight lo
constexpr int P_QKVB = 24576;    // [96]
constexpr int P_QKVA = 24672;    // [96]
constexpr int P_DWB  = 24768;    // ushort[3][9][32oc][32ic] dconv weights bf16 (13824 f32)
constexpr int P_DB   = 52416;    // [3][32]
constexpr int P_OWB  = 52512;    // ushort[256][96] out weight bf16
constexpr int P_OB   = 77088;    // [256]
constexpr int P_OA   = 77344;    // [1]
constexpr int PLANE  = Bb * ICn * HWn;       // 6,553,600
constexpr int OFF_Q  = 77824;
constexpr int OFF_K  = OFF_Q + PLANE;
constexpr int OFF_V  = OFF_Q + 2 * PLANE;    // u16 Vt[8][160][176][32] bf16 (ic-contiguous, w-padded)
constexpr int OFF_T  = OFF_Q + 3 * PLANE;    // u16 t_frag[3][1280][5120] (bf16 MFMA A-frag image)
constexpr int OFF_TPF= OFF_T + (3 * PLANE) / 2;  // u16 tp[3][8][32][25600] planar bf16
constexpr int OFF_CAT= OFF_Q + 6 * PLANE;    // ushort[3*PLANE] (bf16)

typedef unsigned short u16;
typedef short bf16x8 __attribute__((ext_vector_type(8)));
typedef float f32x4  __attribute__((ext_vector_type(4)));

__device__ __forceinline__ unsigned f2b(float x) {
    unsigned u = __float_as_uint(x);
    return (u + 0x7FFFu + ((u >> 16) & 1u)) >> 16;   // RNE f32->bf16
}
__device__ __forceinline__ float b2f(unsigned b) { return __uint_as_float(b << 16); }

struct InPtrs { const float* p[40]; };

// ---------------- prep: fold BN into weights/biases ----------------
__global__ void k_prep(InPtrs in, float* __restrict__ ws) {
    int idx = blockIdx.x * 256 + threadIdx.x;
    if (idx < 24576) {
        int oc = idx >> 8, c = idx & 255;
        int z = oc >> 5, o = oc & 31;
        const float* wz = in.p[1 + 6 * z];
        float s = in.p[2 + 6 * z][o] * rsqrtf(in.p[5 + 6 * z][o] + EPSf);
        float wf = wz[o * 256 + c] * s;
        unsigned hi = f2b(wf);
        unsigned lo = f2b(wf - b2f(hi));
        ((u16*)(ws + P_WQH))[oc * 256 + c] = (u16)hi;
        ((u16*)(ws + P_WQL))[oc * 256 + c] = (u16)lo;
    } else if (idx < 24672) {
        int oc = idx - 24576; int z = oc >> 5, o = oc & 31;
        float s = in.p[2 + 6 * z][o] * rsqrtf(in.p[5 + 6 * z][o] + EPSf);
        ws[P_QKVB + oc] = in.p[3 + 6 * z][o] - in.p[4 + 6 * z][o] * s;
    } else if (idx < 24768) {
        int oc = idx - 24672; int z = oc >> 5;
        ws[P_QKVA + oc] = in.p[6 + 6 * z][0];
    } else if (idx < 52416) {
        int j = idx - 24768;
        int d = j / 9216, r2 = j % 9216;
        int oc = r2 & 31; int tmp = r2 >> 5;
        int kx = tmp % 3; tmp /= 3; int ky = tmp % 3; int ic2 = tmp / 3;
        const float* wd = in.p[19 + 5 * d];
        float s = in.p[20 + 5 * d][oc] * rsqrtf(in.p[23 + 5 * d][oc] + EPSf);
        float wf = wd[((oc * 32 + ic2) * 3 + ky) * 3 + kx] * s;
        ((u16*)(ws + P_DWB))[((d * 9 + ky * 3 + kx) * 32 + oc) * 32 + ic2] = (u16)f2b(wf);
    } else if (idx < 52512) {
        int j = idx - 52416; int d = j >> 5, oc = j & 31;
        float s = in.p[20 + 5 * d][oc] * rsqrtf(in.p[23 + 5 * d][oc] + EPSf);
        ws[P_DB + j] = in.p[21 + 5 * d][oc] - in.p[22 + 5 * d][oc] * s;
    } else if (idx < 77088) {
        int j2 = idx - 52512; int c = j2 / 96;
        float s = in.p[35][c] * rsqrtf(in.p[38][c] + EPSf);
        ((u16*)(ws + P_OWB))[j2] = (u16)f2b(in.p[34][j2] * s);
    } else if (idx < 77344) {
        int c = idx - 77088;
        float s = in.p[35][c] * rsqrtf(in.p[38][c] + EPSf);
        ws[P_OB + c] = in.p[36][c] - in.p[37][c] * s;
    } else if (idx == 77344) {
        ws[P_OA] = in.p[39][0];
    }
}

// ---------------- zero Vt w-pads: Vt[b][h][0..8)|[168..176)][ic] ----------------
__global__ __launch_bounds__(64) void k_vpad(float* __restrict__ ws) {
    u16* Vt = (u16*)(ws + OFF_V);
    size_t base = (size_t)blockIdx.x * 176 * 32;    // bh = 0..1279
    int t = threadIdx.x;
    int off = (t < 32) ? t * 8 : (168 * 32 + (t - 32) * 8);
    uint4 z = {0u, 0u, 0u, 0u};
    *(uint4*)(Vt + base + off) = z;
}

// ---------------- q/k/v 1x1 conv: bf16 hi/lo MFMA GEMM M=96,K=256,N=204800 ----------------
__global__ __launch_bounds__(256) void k_qkv(const float* __restrict__ feat,
                                             float* __restrict__ ws) {
    __shared__ u16 BhS[8192];   // 16 slots(ks,nt) x 64 lanes x 8 bf16
    __shared__ u16 BlS[8192];
    const int tid = threadIdx.x;
    const int wv = tid >> 6, l = tid & 63;
    const int g = l >> 4, c15 = l & 15;
    const int n0 = blockIdx.x * 128;
    const int b = n0 / HWn, hw0 = n0 % HWn;
    const float* fbase = feat + (size_t)b * Cc * HWn + hw0;
    const u16* __restrict__ WQH = (const u16*)(ws + P_WQH);
    const u16* __restrict__ WQL = (const u16*)(ws + P_WQL);
    f32x4 acc[6][2];
    f32x4 z4 = {0.f, 0.f, 0.f, 0.f};
#pragma unroll
    for (int mt = 0; mt < 6; mt++) { acc[mt][0] = z4; acc[mt][1] = z4; }

    for (int kc = 0; kc < 4; kc++) {
        __syncthreads();
#pragma unroll
        for (int ss = 0; ss < 4; ss++) {      // 1024 slots
            int s = tid + ss * 256;
            int sl = s & 63, si = s >> 6;     // si = ks*8+nt
            int k0 = kc * 64 + (si >> 3) * 32 + (sl >> 4) * 8;
            int nn = (si & 7) * 16 + (sl & 15);
            const float* gp = fbase + (size_t)k0 * HWn + nn;
            unsigned hb[8], lb[8];
#pragma unroll
            for (int v = 0; v < 8; v++) {
                float x = gp[(size_t)v * HWn];
                hb[v] = f2b(x);
                lb[v] = f2b(x - b2f(hb[v]));
            }
            uint4 hv = {hb[0] | (hb[1] << 16), hb[2] | (hb[3] << 16),
                        hb[4] | (hb[5] << 16), hb[6] | (hb[7] << 16)};
            uint4 lv = {lb[0] | (lb[1] << 16), lb[2] | (lb[3] << 16),
                        lb[4] | (lb[5] << 16), lb[6] | (lb[7] << 16)};
            *(uint4*)(&BhS[(si * 64 + sl) * 8]) = hv;
            *(uint4*)(&BlS[(si * 64 + sl) * 8]) = lv;
        }
        __syncthreads();
#pragma unroll
        for (int ks = 0; ks < 2; ks++) {
            bf16x8 bh[2], bl[2];
#pragma unroll
            for (int ntl = 0; ntl < 2; ntl++) {
                int nt = wv * 2 + ntl;
                bh[ntl] = *(const bf16x8*)(&BhS[((ks * 8 + nt) * 64 + l) * 8]);
                bl[ntl] = *(const bf16x8*)(&BlS[((ks * 8 + nt) * 64 + l) * 8]);
            }
#pragma unroll
            for (int mt = 0; mt < 6; mt++) {
                int arow = (16 * mt + c15) * 256 + kc * 64 + ks * 32 + g * 8;
                bf16x8 ah = *(const bf16x8*)(WQH + arow);
                bf16x8 al = *(const bf16x8*)(WQL + arow);
#pragma unroll
                for (int ntl = 0; ntl < 2; ntl++) {
                    acc[mt][ntl] = __builtin_amdgcn_mfma_f32_16x16x32_bf16(ah, bh[ntl], acc[mt][ntl], 0, 0, 0);
                    acc[mt][ntl] = __builtin_amdgcn_mfma_f32_16x16x32_bf16(ah, bl[ntl], acc[mt][ntl], 0, 0, 0);
                    acc[mt][ntl] = __builtin_amdgcn_mfma_f32_16x16x32_bf16(al, bh[ntl], acc[mt][ntl], 0, 0, 0);
                }
            }
        }
    }
    // epilogue: bias + PReLU; q/k -> f32 planar, v -> bf16 Vt[b][h][w+8][ic]
    u16* vt = (u16*)(ws + OFF_V);
#pragma unroll
    for (int mt = 0; mt < 6; mt++)
#pragma unroll
        for (int ntl = 0; ntl < 2; ntl++) {
            int pos = hw0 + (wv * 2 + ntl) * 16 + c15;
            if (mt < 4) {
#pragma unroll
                for (int jr = 0; jr < 4; jr++) {
                    int oc = 16 * mt + 4 * g + jr;
                    float bb = ws[P_QKVB + oc];
                    float aa = ws[P_QKVA + oc];
                    float y = acc[mt][ntl][jr] + bb;
                    y = y >= 0.f ? y : aa * y;
                    int z = oc >> 5, o = oc & 31;
                    ws[OFF_Q + (size_t)z * PLANE + ((size_t)b * ICn + o) * HWn + pos] = y;
                }
            } else {
                int h = pos / 160, w2 = pos % 160;
                unsigned r[2];
#pragma unroll
                for (int p = 0; p < 2; p++) {
                    int oc = 16 * mt + 4 * g + 2 * p;
                    float y0 = acc[mt][ntl][2 * p]     + ws[P_QKVB + oc];
                    float y1 = acc[mt][ntl][2 * p + 1] + ws[P_QKVB + oc + 1];
                    float a0 = ws[P_QKVA + oc], a1 = ws[P_QKVA + oc + 1];
                    y0 = y0 >= 0.f ? y0 : a0 * y0;
                    y1 = y1 >= 0.f ? y1 : a1 * y1;
                    r[p] = f2b(y0) | (f2b(y1) << 16);
                }
                size_t a = ((size_t)(b * 160 + h) * 176 + w2 + 8) * 32 + (mt - 4) * 16 + 4 * g;
                uint2 dd; dd.x = r[0]; dd.y = r[1];
                *(uint2*)(vt + a) = dd;
            }
        }
}

// ---------------- dilated 3x3 convs: MFMA over ic (A=V fragments from global) ----------------
// block 256 = 4 waves; block = 2 h-rows of one (b,d); wave: 5 pixel-tiles of 16.
__global__ __launch_bounds__(256) void k_dconv(float* __restrict__ ws) {
    const int tid = threadIdx.x;
    const int wv = tid >> 6, l = tid & 63;
    const int g = l >> 4, c15 = l & 15;
    const int b = blockIdx.y;
    const int d = blockIdx.z;
    const int dil = 1 + 2 * d;
    const int h0 = blockIdx.x * 2;
    const u16* __restrict__ WB = (const u16*)(ws + P_DWB) + d * 9 * 32 * 32;
    bf16x8 wb[9][2];
#pragma unroll
    for (int tap = 0; tap < 9; tap++)
#pragma unroll
        for (int n = 0; n < 2; n++)
            wb[tap][n] = *(const bf16x8*)(WB + ((size_t)tap * 32 + n * 16 + c15) * 32 + g * 8);
    const u16* __restrict__ Vt = (const u16*)(ws + OFF_V) + (size_t)b * 160 * 176 * 32;
    const float bias0 = ws[P_DB + d * 32 + c15];
    const float bias1 = ws[P_DB + d * 32 + 16 + c15];
    u16* __restrict__ tp = (u16*)(ws + OFF_TPF) + (size_t)(d * Bb + b) * ICn * HWn;
    f32x4 z4 = {0.f, 0.f, 0.f, 0.f};

    for (int t5 = 0; t5 < 5; t5++) {
        int t = wv * 5 + t5;
        int h = h0 + (t >= 10);
        int w0 = (t % 10) * 16;
        f32x4 acc0 = z4, acc1 = z4;
#pragma unroll
        for (int ky = 0; ky < 3; ky++) {
            int hh = h + dil * (ky - 1);
            if ((unsigned)hh >= 160u) continue;
            const u16* row = Vt + (size_t)hh * 176 * 32;
#pragma unroll
            for (int kx = 0; kx < 3; kx++) {
                int wbase = w0 + dil * (kx - 1) + 8;
                bf16x8 av = *(const bf16x8*)(row + (size_t)(wbase + c15) * 32 + g * 8);
                acc0 = __builtin_amdgcn_mfma_f32_16x16x32_bf16(av, wb[ky * 3 + kx][0], acc0, 0, 0, 0);
                acc1 = __builtin_amdgcn_mfma_f32_16x16x32_bf16(av, wb[ky * 3 + kx][1], acc1, 0, 0, 0);
            }
        }
        // D: lane c15 = oc (per n-tile), rows = pixels w0+4g+j
        size_t pixb = (size_t)h * 160 + w0 + 4 * g;
        uint2 o0, o1;
        o0.x = f2b(fmaxf(acc0[0] + bias0, 0.f)) | (f2b(fmaxf(acc0[1] + bias0, 0.f)) << 16);
        o0.y = f2b(fmaxf(acc0[2] + bias0, 0.f)) | (f2b(fmaxf(acc0[3] + bias0, 0.f)) << 16);
        o1.x = f2b(fmaxf(acc1[0] + bias1, 0.f)) | (f2b(fmaxf(acc1[1] + bias1, 0.f)) << 16);
        o1.y = f2b(fmaxf(acc1[2] + bias1, 0.f)) | (f2b(fmaxf(acc1[3] + bias1, 0.f)) << 16);
        *(uint2*)(tp + (size_t)c15 * HWn + pixb) = o0;
        *(uint2*)(tp + (size_t)(16 + c15) * HWn + pixb) = o1;
    }
}

// ---------------- t re-layout: planar bf16 -> MFMA A-frag image ----------------
__global__ __launch_bounds__(256) void k_tfrag(float* __restrict__ ws) {
    __shared__ u16 fr[4][5120];
    const int tid = threadIdx.x;
    const int wq = blockIdx.x;      // 0..39
    const int b  = blockIdx.y;      // 0..7
    const int d  = blockIdx.z;      // 0..2
    const int w0 = wq * 4;
    const u16* __restrict__ tp = (const u16*)(ws + OFF_TPF) + (size_t)(d * Bb + b) * ICn * HWn;
    for (int i = tid; i < 5120; i += 256) {
        int ic = i / 160, h = i % 160;
        uint2 v = *(const uint2*)(tp + (size_t)ic * HWn + h * Ww + w0);
        fr[0][i] = (u16)(v.x & 0xFFFFu);
        fr[1][i] = (u16)(v.x >> 16);
        fr[2][i] = (u16)(v.y & 0xFFFFu);
        fr[3][i] = (u16)(v.y >> 16);
    }
    __syncthreads();
    u16* __restrict__ tf = (u16*)(ws + OFF_T);
#pragma unroll
    for (int it = 0; it < 10; it++) {
        int W = tid + it * 256;          // 0..2559
        int s = W / 640, word = W % 640;
        int slot = word >> 6, lane = word & 63;
        int jc = (lane & 15) | ((slot / 5) << 4);
        int h2b = ((slot % 5) << 5) | (((lane >> 4) & 3) << 3);
        unsigned r[4];
#pragma unroll
        for (int p = 0; p < 4; p++) {
            int f0 = (h2b + 2 * p) * 32 + jc;
            unsigned lo = fr[s][f0];
            unsigned hi = fr[s][f0 + 32];
            r[p] = lo | (hi << 16);
        }
        uint4 o4 = {r[0], r[1], r[2], r[3]};
        *(uint4*)(tf + ((size_t)d * 1280 + b * 160 + w0 + s) * 5120 + word * 8) = o4;
    }
}

// ---------------- attention: MFMA bf16; t read as fragments directly from global ----------------
__device__ __forceinline__ void stage_qk_hilo(const float* __restrict__ g,
                                              char* hi_buf, char* lo_buf, int tid) {
#pragma unroll
    for (int ss = 0; ss < 2; ss++) {
        int s = tid + ss * 320;          // 640 slots = 10 tiles x 64 lanes
        int l = s & 63, rt = s >> 6;
        int h = 16 * rt + (l & 15);
        int icb = (l >> 4) * 8;
        const float* gp = g + (size_t)icb * HWn + h * Ww;
        unsigned hb[8], lb[8];
#pragma unroll
        for (int v = 0; v < 8; v++) {
            float x = gp[(size_t)v * HWn];
            hb[v] = f2b(x);
            lb[v] = f2b(x - b2f(hb[v]));
        }
        uint4 hv = {hb[0] | (hb[1] << 16), hb[2] | (hb[3] << 16),
                    hb[4] | (hb[5] << 16), hb[6] | (hb[7] << 16)};
        uint4 lv = {lb[0] | (lb[1] << 16), lb[2] | (lb[3] << 16),
                    lb[4] | (lb[5] << 16), lb[6] | (lb[7] << 16)};
        *(uint4*)(hi_buf + s * 16) = hv;
        *(uint4*)(lo_buf + s * 16) = lv;
    }
}

__global__ __launch_bounds__(320) void k_att(float* __restrict__ ws) {
    extern __shared__ char smem[];
    char* q_hi = smem;               // 10240 B each
    char* q_lo = smem + 10240;
    char* k_hi = smem + 20480;
    char* k_lo = smem + 30720;
    char* Sb   = smem;               // 51200 B, reuses q/k region after barrier
    const int tid = threadIdx.x;
    const int bid = blockIdx.x;
    const int r8 = bid & 7, qq = bid >> 3;   // XCD swizzle
    const int b = qq / 20;
    const int w = r8 * 20 + (qq % 20);
    const int bw = b * Ww + w;
    const int wv = tid >> 6;
    const int l  = tid & 63;
    const int g  = l >> 4;
    const int c  = l & 15;

    const float* qg = ws + OFF_Q + (size_t)b * ICn * HWn + w;
    const float* kg = ws + OFF_K + (size_t)b * ICn * HWn + w;
    stage_qk_hilo(qg, q_hi, q_lo, tid);
    stage_qk_hilo(kg, k_hi, k_lo, tid);
    __syncthreads();

    bf16x8 bq[2][2];
#pragma unroll
    for (int ct = 0; ct < 2; ct++) {
        int tau = 2 * wv + ct;
        bq[ct][0] = *(bf16x8*)(q_hi + (tau * 64 + l) * 16);
        bq[ct][1] = *(bf16x8*)(q_lo + (tau * 64 + l) * 16);
    }
    f32x4 acc[10][2];
    f32x4 z4 = {0.f, 0.f, 0.f, 0.f};
#pragma unroll
    for (int rt = 0; rt < 10; rt++) { acc[rt][0] = z4; acc[rt][1] = z4; }
#pragma unroll
    for (int rt = 0; rt < 10; rt++) {
        bf16x8 ah = *(bf16x8*)(k_hi + (rt * 64 + l) * 16);
        bf16x8 al = *(bf16x8*)(k_lo + (rt * 64 + l) * 16);
#pragma unroll
        for (int ct = 0; ct < 2; ct++) {
            acc[rt][ct] = __builtin_amdgcn_mfma_f32_16x16x32_bf16(ah, bq[ct][0], acc[rt][ct], 0, 0, 0);
            acc[rt][ct] = __builtin_amdgcn_mfma_f32_16x16x32_bf16(ah, bq[ct][1], acc[rt][ct], 0, 0, 0);
            acc[rt][ct] = __builtin_amdgcn_mfma_f32_16x16x32_bf16(al, bq[ct][0], acc[rt][ct], 0, 0, 0);
        }
    }
    __syncthreads();   // all q/k reads done; Sb region free

    float mx[2] = {-3.4e38f, -3.4e38f};
#pragma unroll
    for (int rt = 0; rt < 10; rt++)
#pragma unroll
        for (int ct = 0; ct < 2; ct++)
#pragma unroll
            for (int j = 0; j < 4; j++) mx[ct] = fmaxf(mx[ct], acc[rt][ct][j]);
#pragma unroll
    for (int ct = 0; ct < 2; ct++) {
        mx[ct] = fmaxf(mx[ct], __shfl_xor(mx[ct], 16));
        mx[ct] = fmaxf(mx[ct], __shfl_xor(mx[ct], 32));
    }
    float sm[2] = {0.f, 0.f};
#pragma unroll
    for (int rt = 0; rt < 10; rt++)
#pragma unroll
        for (int ct = 0; ct < 2; ct++)
#pragma unroll
            for (int j = 0; j < 4; j++) {
                float e = __expf(acc[rt][ct][j] - mx[ct]);
                acc[rt][ct][j] = e;
                sm[ct] += e;
            }
#pragma unroll
    for (int ct = 0; ct < 2; ct++) {
        sm[ct] += __shfl_xor(sm[ct], 16);
        sm[ct] += __shfl_xor(sm[ct], 32);
    }
    float inv[2] = {1.f / sm[0], 1.f / sm[1]};

#pragma unroll
    for (int rt = 0; rt < 10; rt++) {
#pragma unroll
        for (int ct = 0; ct < 2; ct++) {
            float p0 = acc[rt][ct][0] * inv[ct];
            float p1 = acc[rt][ct][1] * inv[ct];
            float p2 = acc[rt][ct][2] * inv[ct];
            float p3 = acc[rt][ct][3] * inv[ct];
            unsigned d0 = f2b(p0) | (f2b(p1) << 16);
            unsigned d1 = f2b(p2) | (f2b(p3) << 16);
            int Lf = c + 16 * (2 * (rt & 1) + (g >> 1));
            char* dst = Sb + (((wv * 2 + ct) * 5 + (rt >> 1)) * 64 + Lf) * 16 + 8 * (g & 1);
            uint2 dd; dd.x = d0; dd.y = d1;
            *(uint2*)dst = dd;
        }
    }
    __syncthreads();

    const u16* tf = (const u16*)(ws + OFF_T);
    u16* catb = (u16*)(ws + OFF_CAT);
    for (int d = 0; d < 3; d++) {
        const u16* tfd = tf + ((size_t)d * (Bb * Ww) + bw) * 5120;
        f32x4 po[2][2];
        po[0][0] = z4; po[0][1] = z4; po[1][0] = z4; po[1][1] = z4;
#pragma unroll
        for (int ks = 0; ks < 5; ks++) {
            bf16x8 a0 = *(const bf16x8*)(tfd + ((0 * 5 + ks) * 64 + l) * 8);   // coalesced 16B/lane
            bf16x8 a1 = *(const bf16x8*)(tfd + ((1 * 5 + ks) * 64 + l) * 8);
            bf16x8 s0 = *(bf16x8*)(Sb + (((wv * 2 + 0) * 5 + ks) * 64 + l) * 16);
            bf16x8 s1 = *(bf16x8*)(Sb + (((wv * 2 + 1) * 5 + ks) * 64 + l) * 16);
            po[0][0] = __builtin_amdgcn_mfma_f32_16x16x32_bf16(a0, s0, po[0][0], 0, 0, 0);
            po[0][1] = __builtin_amdgcn_mfma_f32_16x16x32_bf16(a0, s1, po[0][1], 0, 0, 0);
            po[1][0] = __builtin_amdgcn_mfma_f32_16x16x32_bf16(a1, s0, po[1][0], 0, 0, 0);
            po[1][1] = __builtin_amdgcn_mfma_f32_16x16x32_bf16(a1, s1, po[1][1], 0, 0, 0);
        }
#pragma unroll
        for (int jt = 0; jt < 2; jt++)
#pragma unroll
            for (int ct = 0; ct < 2; ct++) {
                int h1 = 32 * wv + 16 * ct + c;
                size_t idx = (size_t)d * PLANE + (size_t)bw * 5120 + h1 * 32 + 16 * jt + 4 * g;
                f32x4 v = po[jt][ct];
                uint2 dd;
                dd.x = f2b(v[0]) | (f2b(v[1]) << 16);
                dd.y = f2b(v[2]) | (f2b(v[3]) << 16);
                *(uint2*)(catb + idx) = dd;
            }
    }
}

// ---------------- output 1x1 conv: bf16 MFMA GEMM M=256,K=96,N=204800 ----------------
__global__ __launch_bounds__(256) void k_out(const float* __restrict__ feat,
                                             const float* __restrict__ ws,
                                             float* __restrict__ out) {
    __shared__ u16 Bs[12288];   // 24 slots(ks,nt) x 64 lanes x 8 bf16
    const int tid = threadIdx.x;
    const int wv = tid >> 6, l = tid & 63;
    const int g = l >> 4, c15 = l & 15;
    const int n0 = blockIdx.x * 128;
    const int b = n0 / HWn, hw0 = n0 % HWn;
    const u16* __restrict__ CATb = (const u16*)(ws + OFF_CAT);
    const u16* __restrict__ OWB = (const u16*)(ws + P_OWB);

#pragma unroll
    for (int ss = 0; ss < 6; ss++) {
        int s = tid + ss * 256;
        int sl = s & 63, si = s >> 6;    // si = ks*8+nt, 0..23
        int p = (si & 7) * 16 + (sl & 15);
        int hw = hw0 + p;
        int h = hw / Ww, w2 = hw % Ww;
        int j = (si >> 3) * 32 + (sl >> 4) * 8;
        size_t flat = ((size_t)(b * Ww + w2) * Hh + h) * 96 + j;
        *(uint4*)(&Bs[(si * 64 + sl) * 8]) = *(const uint4*)(CATb + flat);
    }
    bf16x8 af[4][3];
#pragma unroll
    for (int mt = 0; mt < 4; mt++)
#pragma unroll
        for (int ks = 0; ks < 3; ks++)
            af[mt][ks] = *(const bf16x8*)(OWB + (wv * 64 + mt * 16 + c15) * 96 + ks * 32 + g * 8);
    __syncthreads();
    const float alpha = ws[P_OA];

    f32x4 z4 = {0.f, 0.f, 0.f, 0.f};
#pragma unroll
    for (int np = 0; np < 2; np++) {
        f32x4 acc[4][4];
#pragma unroll
        for (int mt = 0; mt < 4; mt++)
#pragma unroll
            for (int ntl = 0; ntl < 4; ntl++) acc[mt][ntl] = z4;
#pragma unroll
        for (int ks = 0; ks < 3; ks++) {
            bf16x8 bf_[4];
#pragma unroll
            for (int ntl = 0; ntl < 4; ntl++)
                bf_[ntl] = *(const bf16x8*)(&Bs[((ks * 8 + np * 4 + ntl) * 64 + l) * 8]);
#pragma unroll
            for (int mt = 0; mt < 4; mt++)
#pragma unroll
                for (int ntl = 0; ntl < 4; ntl++)
                    acc[mt][ntl] = __builtin_amdgcn_mfma_f32_16x16x32_bf16(af[mt][ks], bf_[ntl], acc[mt][ntl], 0, 0, 0);
        }
#pragma unroll
        for (int mt = 0; mt < 4; mt++)
#pragma unroll
            for (int ntl = 0; ntl < 4; ntl++) {
                int p = (np * 4 + ntl) * 16 + c15;
#pragma unroll
                for (int jr = 0; jr < 4; jr++) {
                    int cch = wv * 64 + mt * 16 + 4 * g + jr;
                    size_t base = ((size_t)b * Cc + cch) * HWn + hw0 + p;
                    float y = acc[mt][ntl][jr] + ws[P_OB + cch] + feat[base];
                    out[base] = y >= 0.f ? y : alpha * y;
                }
            }
    }
}

extern "C" void kernel_launch(void* const* d_in, const int* in_sizes, int n_in,
                              void* d_out, int out_size, void* d_ws, size_t ws_size,
                              hipStream_t stream) {
    InPtrs ip;
    for (int i = 0; i < 40; i++) ip.p[i] = (const float*)d_in[i];
    float* ws = (float*)d_ws;
    const float* feat = (const float*)d_in[0];
    float* out = (float*)d_out;

    k_prep<<<304, 256, 0, stream>>>(ip, ws);
    k_vpad<<<1280, 64, 0, stream>>>(ws);
    k_qkv<<<1600, 256, 0, stream>>>(feat, ws);
    k_dconv<<<dim3(80, 8, 3), 256, 0, stream>>>(ws);
    k_tfrag<<<dim3(40, 8, 3), 256, 0, stream>>>(ws);
    (void)hipFuncSetAttribute(reinterpret_cast<const void*>(k_att),
                              hipFuncAttributeMaxDynamicSharedMemorySize, 51200);
    k_att<<<1280, 320, 51200, stream>>>(ws);
    k_out<<<1600, 256, 0, stream>>>(feat, ws, out);
}

// Round 8
// 459.513 us; speedup vs baseline: 1.4803x; 1.0200x over previous
//
#include <hip/hip_runtime.h>

constexpr int Hh = 160, Ww = 160, Bb = 8, Cc = 256, ICn = 32;
constexpr int HWn = Hh * Ww;                 // 25600
constexpr float EPSf = 1e-5f;

// ws float offsets
constexpr int P_WQH  = 0;        // ushort[96][256] qkv weight hi
constexpr int P_WQL  = 12288;    // ushort[96][256] qkv weight lo
constexpr int P_QKVB = 24576;    // [96]
constexpr int P_QKVA = 24672;    // [96]
constexpr int P_DWB  = 24768;    // ushort[3][9][32oc][32ic] dconv weights bf16
constexpr int P_DB   = 52416;    // [3][32]
constexpr int P_OWB  = 52512;    // ushort[256][96] out weight bf16
constexpr int P_OB   = 77088;    // [256]
constexpr int P_OA   = 77344;    // [1]
constexpr int PLANE  = Bb * ICn * HWn;       // 6,553,600
constexpr int OFF_Q  = 77824;
constexpr int OFF_K  = OFF_Q + PLANE;
constexpr int OFF_V  = OFF_Q + 2 * PLANE;    // u16 Vt[8][160][176][32] bf16 (ic-contiguous, w-padded)
constexpr int OFF_T  = OFF_Q + 3 * PLANE;    // u16 t_frag[3][1280][5120] (bf16 MFMA A-frag image)
constexpr int OFF_TPF= OFF_T + (3 * PLANE) / 2;  // u16 tp[3][8][32][25600] planar bf16
constexpr int OFF_CAT= OFF_Q + 6 * PLANE;    // ushort[3*PLANE] (bf16)

typedef unsigned short u16;
typedef short bf16x8 __attribute__((ext_vector_type(8)));
typedef float f32x4  __attribute__((ext_vector_type(4)));

__device__ __forceinline__ unsigned f2b(float x) {
    unsigned u = __float_as_uint(x);
    return (u + 0x7FFFu + ((u >> 16) & 1u)) >> 16;   // RNE f32->bf16
}
__device__ __forceinline__ float b2f(unsigned b) { return __uint_as_float(b << 16); }

#define GLOAD_LDS16(gp, lp) __builtin_amdgcn_global_load_lds( \
    (const __attribute__((address_space(1))) void*)(gp), \
    (__attribute__((address_space(3))) void*)(lp), 16, 0, 0)

struct InPtrs { const float* p[40]; };

// ---------------- prep: fold BN into weights/biases ----------------
__global__ void k_prep(InPtrs in, float* __restrict__ ws) {
    int idx = blockIdx.x * 256 + threadIdx.x;
    if (idx < 24576) {
        int oc = idx >> 8, c = idx & 255;
        int z = oc >> 5, o = oc & 31;
        const float* wz = in.p[1 + 6 * z];
        float s = in.p[2 + 6 * z][o] * rsqrtf(in.p[5 + 6 * z][o] + EPSf);
        float wf = wz[o * 256 + c] * s;
        unsigned hi = f2b(wf);
        unsigned lo = f2b(wf - b2f(hi));
        ((u16*)(ws + P_WQH))[oc * 256 + c] = (u16)hi;
        ((u16*)(ws + P_WQL))[oc * 256 + c] = (u16)lo;
    } else if (idx < 24672) {
        int oc = idx - 24576; int z = oc >> 5, o = oc & 31;
        float s = in.p[2 + 6 * z][o] * rsqrtf(in.p[5 + 6 * z][o] + EPSf);
        ws[P_QKVB + oc] = in.p[3 + 6 * z][o] - in.p[4 + 6 * z][o] * s;
    } else if (idx < 24768) {
        int oc = idx - 24672; int z = oc >> 5;
        ws[P_QKVA + oc] = in.p[6 + 6 * z][0];
    } else if (idx < 52416) {
        int j = idx - 24768;
        int d = j / 9216, r2 = j % 9216;
        int oc = r2 & 31; int tmp = r2 >> 5;
        int kx = tmp % 3; tmp /= 3; int ky = tmp % 3; int ic2 = tmp / 3;
        const float* wd = in.p[19 + 5 * d];
        float s = in.p[20 + 5 * d][oc] * rsqrtf(in.p[23 + 5 * d][oc] + EPSf);
        float wf = wd[((oc * 32 + ic2) * 3 + ky) * 3 + kx] * s;
        ((u16*)(ws + P_DWB))[((d * 9 + ky * 3 + kx) * 32 + oc) * 32 + ic2] = (u16)f2b(wf);
    } else if (idx < 52512) {
        int j = idx - 52416; int d = j >> 5, oc = j & 31;
        float s = in.p[20 + 5 * d][oc] * rsqrtf(in.p[23 + 5 * d][oc] + EPSf);
        ws[P_DB + j] = in.p[21 + 5 * d][oc] - in.p[22 + 5 * d][oc] * s;
    } else if (idx < 77088) {
        int j2 = idx - 52512; int c = j2 / 96;
        float s = in.p[35][c] * rsqrtf(in.p[38][c] + EPSf);
        ((u16*)(ws + P_OWB))[j2] = (u16)f2b(in.p[34][j2] * s);
    } else if (idx < 77344) {
        int c = idx - 77088;
        float s = in.p[35][c] * rsqrtf(in.p[38][c] + EPSf);
        ws[P_OB + c] = in.p[36][c] - in.p[37][c] * s;
    } else if (idx == 77344) {
        ws[P_OA] = in.p[39][0];
    }
}

// ---------------- zero Vt w-pads ----------------
__global__ __launch_bounds__(64) void k_vpad(float* __restrict__ ws) {
    u16* Vt = (u16*)(ws + OFF_V);
    size_t base = (size_t)blockIdx.x * 176 * 32;    // bh = 0..1279
    int t = threadIdx.x;
    int off = (t < 32) ? t * 8 : (168 * 32 + (t - 32) * 8);
    uint4 z = {0u, 0u, 0u, 0u};
    *(uint4*)(Vt + base + off) = z;
}

// ---------------- q/k/v 1x1 conv: async-staged dbuf MFMA GEMM M=96,K=256,N=204800 ----------------
// grid 800, block 256 = 4 waves; N-tile 256, K chunked by 32, 2-phase pipeline.
__global__ __launch_bounds__(256) void k_qkv(const float* __restrict__ feat,
                                             float* __restrict__ ws) {
    extern __shared__ float FS[];    // [2][32*256] f32 = 64 KB
    const int tid = threadIdx.x;
    const int wv = tid >> 6, l = tid & 63;
    const int g = l >> 4, c15 = l & 15;
    const int n0 = blockIdx.x * 256;
    const int b = n0 / HWn, hw0 = n0 % HWn;
    const float* fbase = feat + (size_t)b * Cc * HWn + hw0;
    const u16* __restrict__ WQH = (const u16*)(ws + P_WQH);
    const u16* __restrict__ WQL = (const u16*)(ws + P_WQL);

    f32x4 acc[6][4];
    f32x4 z4 = {0.f, 0.f, 0.f, 0.f};
#pragma unroll
    for (int mt = 0; mt < 6; mt++)
#pragma unroll
        for (int i = 0; i < 4; i++) acc[mt][i] = z4;

    // prologue: stage chunk 0 (each instr: one channel row = 1 KB coalesced)
#pragma unroll
    for (int j = 0; j < 8; j++) {
        int r = wv * 8 + j;
        GLOAD_LDS16(fbase + (size_t)r * HWn + l * 4, &FS[r * 256]);
    }
    __syncthreads();

    for (int kc = 0; kc < 8; kc++) {
        // prefetch chunk kc+1 into other buffer (flies under compute)
        if (kc < 7) {
            float* dst = &FS[((kc + 1) & 1) * 8192];
#pragma unroll
            for (int j = 0; j < 8; j++) {
                int r = wv * 8 + j;
                GLOAD_LDS16(fbase + (size_t)((kc + 1) * 32 + r) * HWn + l * 4, dst + r * 256);
            }
        }
        // compute from current buffer
        const float* B = &FS[(kc & 1) * 8192];
        bf16x8 bh[4], bl[4];
#pragma unroll
        for (int i = 0; i < 4; i++) {
            const float* bp = B + (g * 8) * 256 + (wv * 4 + i) * 16 + c15;
            unsigned hw_[4], lw_[4];
#pragma unroll
            for (int v2 = 0; v2 < 4; v2++) {
                float x0 = bp[(2 * v2) * 256];
                float x1 = bp[(2 * v2 + 1) * 256];
                unsigned h0 = f2b(x0), h1 = f2b(x1);
                unsigned l0 = f2b(x0 - b2f(h0)), l1 = f2b(x1 - b2f(h1));
                hw_[v2] = h0 | (h1 << 16);
                lw_[v2] = l0 | (l1 << 16);
            }
            uint4 hv = {hw_[0], hw_[1], hw_[2], hw_[3]};
            uint4 lv = {lw_[0], lw_[1], lw_[2], lw_[3]};
            bh[i] = *(bf16x8*)&hv;
            bl[i] = *(bf16x8*)&lv;
        }
#pragma unroll
        for (int mt = 0; mt < 6; mt++) {
            int arow = (16 * mt + c15) * 256 + kc * 32 + g * 8;
            bf16x8 ah = *(const bf16x8*)(WQH + arow);
            bf16x8 al = *(const bf16x8*)(WQL + arow);
#pragma unroll
            for (int i = 0; i < 4; i++) {
                acc[mt][i] = __builtin_amdgcn_mfma_f32_16x16x32_bf16(ah, bh[i], acc[mt][i], 0, 0, 0);
                acc[mt][i] = __builtin_amdgcn_mfma_f32_16x16x32_bf16(ah, bl[i], acc[mt][i], 0, 0, 0);
                acc[mt][i] = __builtin_amdgcn_mfma_f32_16x16x32_bf16(al, bh[i], acc[mt][i], 0, 0, 0);
            }
        }
        __syncthreads();   // prefetch landed during compute; buffers swap safely
    }

    // epilogue: bias + PReLU; q/k -> f32 planar, v -> bf16 Vt[b][h][w+8][ic]
    u16* vt = (u16*)(ws + OFF_V);
#pragma unroll
    for (int mt = 0; mt < 6; mt++)
#pragma unroll
        for (int i = 0; i < 4; i++) {
            int pos = hw0 + (wv * 4 + i) * 16 + c15;
            if (mt < 4) {
#pragma unroll
                for (int jr = 0; jr < 4; jr++) {
                    int oc = 16 * mt + 4 * g + jr;
                    float bb = ws[P_QKVB + oc];
                    float aa = ws[P_QKVA + oc];
                    float y = acc[mt][i][jr] + bb;
                    y = y >= 0.f ? y : aa * y;
                    int z = oc >> 5, o = oc & 31;
                    ws[OFF_Q + (size_t)z * PLANE + ((size_t)b * ICn + o) * HWn + pos] = y;
                }
            } else {
                int h = pos / 160, w2 = pos % 160;
                unsigned r[2];
#pragma unroll
                for (int p = 0; p < 2; p++) {
                    int oc = 16 * mt + 4 * g + 2 * p;
                    float y0 = acc[mt][i][2 * p]     + ws[P_QKVB + oc];
                    float y1 = acc[mt][i][2 * p + 1] + ws[P_QKVB + oc + 1];
                    float a0 = ws[P_QKVA + oc], a1 = ws[P_QKVA + oc + 1];
                    y0 = y0 >= 0.f ? y0 : a0 * y0;
                    y1 = y1 >= 0.f ? y1 : a1 * y1;
                    r[p] = f2b(y0) | (f2b(y1) << 16);
                }
                size_t a = ((size_t)(b * 160 + h) * 176 + w2 + 8) * 32 + (mt - 4) * 16 + 4 * g;
                uint2 dd; dd.x = r[0]; dd.y = r[1];
                *(uint2*)(vt + a) = dd;
            }
        }
}

// ---------------- dilated 3x3 convs: MFMA over ic (A=V fragments from global) ----------------
__global__ __launch_bounds__(256) void k_dconv(float* __restrict__ ws) {
    const int tid = threadIdx.x;
    const int wv = tid >> 6, l = tid & 63;
    const int g = l >> 4, c15 = l & 15;
    const int b = blockIdx.y;
    const int d = blockIdx.z;
    const int dil = 1 + 2 * d;
    const int h0 = blockIdx.x * 2;
    const u16* __restrict__ WB = (const u16*)(ws + P_DWB) + d * 9 * 32 * 32;
    bf16x8 wb[9][2];
#pragma unroll
    for (int tap = 0; tap < 9; tap++)
#pragma unroll
        for (int n = 0; n < 2; n++)
            wb[tap][n] = *(const bf16x8*)(WB + ((size_t)tap * 32 + n * 16 + c15) * 32 + g * 8);
    const u16* __restrict__ Vt = (const u16*)(ws + OFF_V) + (size_t)b * 160 * 176 * 32;
    const float bias0 = ws[P_DB + d * 32 + c15];
    const float bias1 = ws[P_DB + d * 32 + 16 + c15];
    u16* __restrict__ tp = (u16*)(ws + OFF_TPF) + (size_t)(d * Bb + b) * ICn * HWn;
    f32x4 z4 = {0.f, 0.f, 0.f, 0.f};

    for (int t5 = 0; t5 < 5; t5++) {
        int t = wv * 5 + t5;
        int h = h0 + (t >= 10);
        int w0 = (t % 10) * 16;
        f32x4 acc0 = z4, acc1 = z4;
#pragma unroll
        for (int ky = 0; ky < 3; ky++) {
            int hh = h + dil * (ky - 1);
            if ((unsigned)hh >= 160u) continue;
            const u16* row = Vt + (size_t)hh * 176 * 32;
#pragma unroll
            for (int kx = 0; kx < 3; kx++) {
                int wbase = w0 + dil * (kx - 1) + 8;
                bf16x8 av = *(const bf16x8*)(row + (size_t)(wbase + c15) * 32 + g * 8);
                acc0 = __builtin_amdgcn_mfma_f32_16x16x32_bf16(av, wb[ky * 3 + kx][0], acc0, 0, 0, 0);
                acc1 = __builtin_amdgcn_mfma_f32_16x16x32_bf16(av, wb[ky * 3 + kx][1], acc1, 0, 0, 0);
            }
        }
        size_t pixb = (size_t)h * 160 + w0 + 4 * g;
        uint2 o0, o1;
        o0.x = f2b(fmaxf(acc0[0] + bias0, 0.f)) | (f2b(fmaxf(acc0[1] + bias0, 0.f)) << 16);
        o0.y = f2b(fmaxf(acc0[2] + bias0, 0.f)) | (f2b(fmaxf(acc0[3] + bias0, 0.f)) << 16);
        o1.x = f2b(fmaxf(acc1[0] + bias1, 0.f)) | (f2b(fmaxf(acc1[1] + bias1, 0.f)) << 16);
        o1.y = f2b(fmaxf(acc1[2] + bias1, 0.f)) | (f2b(fmaxf(acc1[3] + bias1, 0.f)) << 16);
        *(uint2*)(tp + (size_t)c15 * HWn + pixb) = o0;
        *(uint2*)(tp + (size_t)(16 + c15) * HWn + pixb) = o1;
    }
}

// ---------------- t re-layout: planar bf16 -> MFMA A-frag image ----------------
__global__ __launch_bounds__(256) void k_tfrag(float* __restrict__ ws) {
    __shared__ u16 fr[4][5120];
    const int tid = threadIdx.x;
    const int wq = blockIdx.x;      // 0..39
    const int b  = blockIdx.y;      // 0..7
    const int d  = blockIdx.z;      // 0..2
    const int w0 = wq * 4;
    const u16* __restrict__ tp = (const u16*)(ws + OFF_TPF) + (size_t)(d * Bb + b) * ICn * HWn;
    for (int i = tid; i < 5120; i += 256) {
        int ic = i / 160, h = i % 160;
        uint2 v = *(const uint2*)(tp + (size_t)ic * HWn + h * Ww + w0);
        fr[0][i] = (u16)(v.x & 0xFFFFu);
        fr[1][i] = (u16)(v.x >> 16);
        fr[2][i] = (u16)(v.y & 0xFFFFu);
        fr[3][i] = (u16)(v.y >> 16);
    }
    __syncthreads();
    u16* __restrict__ tf = (u16*)(ws + OFF_T);
#pragma unroll
    for (int it = 0; it < 10; it++) {
        int W = tid + it * 256;          // 0..2559
        int s = W / 640, word = W % 640;
        int slot = word >> 6, lane = word & 63;
        int jc = (lane & 15) | ((slot / 5) << 4);
        int h2b = ((slot % 5) << 5) | (((lane >> 4) & 3) << 3);
        unsigned r[4];
#pragma unroll
        for (int p = 0; p < 4; p++) {
            int f0 = (h2b + 2 * p) * 32 + jc;
            unsigned lo = fr[s][f0];
            unsigned hi = fr[s][f0 + 32];
            r[p] = lo | (hi << 16);
        }
        uint4 o4 = {r[0], r[1], r[2], r[3]};
        *(uint4*)(tf + ((size_t)d * 1280 + b * 160 + w0 + s) * 5120 + word * 8) = o4;
    }
}

// ---------------- attention: MFMA bf16; t read as fragments directly from global ----------------
__device__ __forceinline__ void stage_qk_hilo(const float* __restrict__ g,
                                              char* hi_buf, char* lo_buf, int tid) {
#pragma unroll
    for (int ss = 0; ss < 2; ss++) {
        int s = tid + ss * 320;          // 640 slots = 10 tiles x 64 lanes
        int l = s & 63, rt = s >> 6;
        int h = 16 * rt + (l & 15);
        int icb = (l >> 4) * 8;
        const float* gp = g + (size_t)icb * HWn + h * Ww;
        unsigned hb[8], lb[8];
#pragma unroll
        for (int v = 0; v < 8; v++) {
            float x = gp[(size_t)v * HWn];
            hb[v] = f2b(x);
            lb[v] = f2b(x - b2f(hb[v]));
        }
        uint4 hv = {hb[0] | (hb[1] << 16), hb[2] | (hb[3] << 16),
                    hb[4] | (hb[5] << 16), hb[6] | (hb[7] << 16)};
        uint4 lv = {lb[0] | (lb[1] << 16), lb[2] | (lb[3] << 16),
                    lb[4] | (lb[5] << 16), lb[6] | (lb[7] << 16)};
        *(uint4*)(hi_buf + s * 16) = hv;
        *(uint4*)(lo_buf + s * 16) = lv;
    }
}

__global__ __launch_bounds__(320) void k_att(float* __restrict__ ws) {
    extern __shared__ char smem[];
    char* q_hi = smem;               // 10240 B each
    char* q_lo = smem + 10240;
    char* k_hi = smem + 20480;
    char* k_lo = smem + 30720;
    char* Sb   = smem;               // 51200 B, reuses q/k region after barrier
    const int tid = threadIdx.x;
    const int bid = blockIdx.x;
    const int r8 = bid & 7, qq = bid >> 3;   // XCD swizzle
    const int b = qq / 20;
    const int w = r8 * 20 + (qq % 20);
    const int bw = b * Ww + w;
    const int wv = tid >> 6;
    const int l  = tid & 63;
    const int g  = l >> 4;
    const int c  = l & 15;

    const float* qg = ws + OFF_Q + (size_t)b * ICn * HWn + w;
    const float* kg = ws + OFF_K + (size_t)b * ICn * HWn + w;
    stage_qk_hilo(qg, q_hi, q_lo, tid);
    stage_qk_hilo(kg, k_hi, k_lo, tid);
    __syncthreads();

    bf16x8 bq[2][2];
#pragma unroll
    for (int ct = 0; ct < 2; ct++) {
        int tau = 2 * wv + ct;
        bq[ct][0] = *(bf16x8*)(q_hi + (tau * 64 + l) * 16);
        bq[ct][1] = *(bf16x8*)(q_lo + (tau * 64 + l) * 16);
    }
    f32x4 acc[10][2];
    f32x4 z4 = {0.f, 0.f, 0.f, 0.f};
#pragma unroll
    for (int rt = 0; rt < 10; rt++) { acc[rt][0] = z4; acc[rt][1] = z4; }
#pragma unroll
    for (int rt = 0; rt < 10; rt++) {
        bf16x8 ah = *(bf16x8*)(k_hi + (rt * 64 + l) * 16);
        bf16x8 al = *(bf16x8*)(k_lo + (rt * 64 + l) * 16);
#pragma unroll
        for (int ct = 0; ct < 2; ct++) {
            acc[rt][ct] = __builtin_amdgcn_mfma_f32_16x16x32_bf16(ah, bq[ct][0], acc[rt][ct], 0, 0, 0);
            acc[rt][ct] = __builtin_amdgcn_mfma_f32_16x16x32_bf16(ah, bq[ct][1], acc[rt][ct], 0, 0, 0);
            acc[rt][ct] = __builtin_amdgcn_mfma_f32_16x16x32_bf16(al, bq[ct][0], acc[rt][ct], 0, 0, 0);
        }
    }
    __syncthreads();   // all q/k reads done; Sb region free

    float mx[2] = {-3.4e38f, -3.4e38f};
#pragma unroll
    for (int rt = 0; rt < 10; rt++)
#pragma unroll
        for (int ct = 0; ct < 2; ct++)
#pragma unroll
            for (int j = 0; j < 4; j++) mx[ct] = fmaxf(mx[ct], acc[rt][ct][j]);
#pragma unroll
    for (int ct = 0; ct < 2; ct++) {
        mx[ct] = fmaxf(mx[ct], __shfl_xor(mx[ct], 16));
        mx[ct] = fmaxf(mx[ct], __shfl_xor(mx[ct], 32));
    }
    float sm[2] = {0.f, 0.f};
#pragma unroll
    for (int rt = 0; rt < 10; rt++)
#pragma unroll
        for (int ct = 0; ct < 2; ct++)
#pragma unroll
            for (int j = 0; j < 4; j++) {
                float e = __expf(acc[rt][ct][j] - mx[ct]);
                acc[rt][ct][j] = e;
                sm[ct] += e;
            }
#pragma unroll
    for (int ct = 0; ct < 2; ct++) {
        sm[ct] += __shfl_xor(sm[ct], 16);
        sm[ct] += __shfl_xor(sm[ct], 32);
    }
    float inv[2] = {1.f / sm[0], 1.f / sm[1]};

#pragma unroll
    for (int rt = 0; rt < 10; rt++) {
#pragma unroll
        for (int ct = 0; ct < 2; ct++) {
            float p0 = acc[rt][ct][0] * inv[ct];
            float p1 = acc[rt][ct][1] * inv[ct];
            float p2 = acc[rt][ct][2] * inv[ct];
            float p3 = acc[rt][ct][3] * inv[ct];
            unsigned d0 = f2b(p0) | (f2b(p1) << 16);
            unsigned d1 = f2b(p2) | (f2b(p3) << 16);
            int Lf = c + 16 * (2 * (rt & 1) + (g >> 1));
            char* dst = Sb + (((wv * 2 + ct) * 5 + (rt >> 1)) * 64 + Lf) * 16 + 8 * (g & 1);
            uint2 dd; dd.x = d0; dd.y = d1;
            *(uint2*)dst = dd;
        }
    }
    __syncthreads();

    const u16* tf = (const u16*)(ws + OFF_T);
    u16* catb = (u16*)(ws + OFF_CAT);
    for (int d = 0; d < 3; d++) {
        const u16* tfd = tf + ((size_t)d * (Bb * Ww) + bw) * 5120;
        f32x4 po[2][2];
        po[0][0] = z4; po[0][1] = z4; po[1][0] = z4; po[1][1] = z4;
#pragma unroll
        for (int ks = 0; ks < 5; ks++) {
            bf16x8 a0 = *(const bf16x8*)(tfd + ((0 * 5 + ks) * 64 + l) * 8);   // coalesced 16B/lane
            bf16x8 a1 = *(const bf16x8*)(tfd + ((1 * 5 + ks) * 64 + l) * 8);
            bf16x8 s0 = *(bf16x8*)(Sb + (((wv * 2 + 0) * 5 + ks) * 64 + l) * 16);
            bf16x8 s1 = *(bf16x8*)(Sb + (((wv * 2 + 1) * 5 + ks) * 64 + l) * 16);
            po[0][0] = __builtin_amdgcn_mfma_f32_16x16x32_bf16(a0, s0, po[0][0], 0, 0, 0);
            po[0][1] = __builtin_amdgcn_mfma_f32_16x16x32_bf16(a0, s1, po[0][1], 0, 0, 0);
            po[1][0] = __builtin_amdgcn_mfma_f32_16x16x32_bf16(a1, s0, po[1][0], 0, 0, 0);
            po[1][1] = __builtin_amdgcn_mfma_f32_16x16x32_bf16(a1, s1, po[1][1], 0, 0, 0);
        }
#pragma unroll
        for (int jt = 0; jt < 2; jt++)
#pragma unroll
            for (int ct = 0; ct < 2; ct++) {
                int h1 = 32 * wv + 16 * ct + c;
                size_t idx = (size_t)d * PLANE + (size_t)bw * 5120 + h1 * 32 + 16 * jt + 4 * g;
                f32x4 v = po[jt][ct];
                uint2 dd;
                dd.x = f2b(v[0]) | (f2b(v[1]) << 16);
                dd.y = f2b(v[2]) | (f2b(v[3]) << 16);
                *(uint2*)(catb + idx) = dd;
            }
    }
}

// ---------------- output 1x1 conv: bf16 MFMA GEMM M=256,K=96,N=204800 ----------------
__global__ __launch_bounds__(256) void k_out(const float* __restrict__ feat,
                                             const float* __restrict__ ws,
                                             float* __restrict__ out) {
    __shared__ u16 Bs[12288];   // 24 slots(ks,nt) x 64 lanes x 8 bf16
    const int tid = threadIdx.x;
    const int wv = tid >> 6, l = tid & 63;
    const int g = l >> 4, c15 = l & 15;
    const int n0 = blockIdx.x * 128;
    const int b = n0 / HWn, hw0 = n0 % HWn;
    const u16* __restrict__ CATb = (const u16*)(ws + OFF_CAT);
    const u16* __restrict__ OWB = (const u16*)(ws + P_OWB);

#pragma unroll
    for (int ss = 0; ss < 6; ss++) {
        int s = tid + ss * 256;
        int sl = s & 63, si = s >> 6;    // si = ks*8+nt, 0..23
        int p = (si & 7) * 16 + (sl & 15);
        int hw = hw0 + p;
        int h = hw / Ww, w2 = hw % Ww;
        int j = (si >> 3) * 32 + (sl >> 4) * 8;
        size_t flat = ((size_t)(b * Ww + w2) * Hh + h) * 96 + j;
        *(uint4*)(&Bs[(si * 64 + sl) * 8]) = *(const uint4*)(CATb + flat);
    }
    bf16x8 af[4][3];
#pragma unroll
    for (int mt = 0; mt < 4; mt++)
#pragma unroll
        for (int ks = 0; ks < 3; ks++)
            af[mt][ks] = *(const bf16x8*)(OWB + (wv * 64 + mt * 16 + c15) * 96 + ks * 32 + g * 8);
    __syncthreads();
    const float alpha = ws[P_OA];

    f32x4 z4 = {0.f, 0.f, 0.f, 0.f};
#pragma unroll
    for (int np = 0; np < 2; np++) {
        f32x4 acc[4][4];
#pragma unroll
        for (int mt = 0; mt < 4; mt++)
#pragma unroll
            for (int ntl = 0; ntl < 4; ntl++) acc[mt][ntl] = z4;
#pragma unroll
        for (int ks = 0; ks < 3; ks++) {
            bf16x8 bf_[4];
#pragma unroll
            for (int ntl = 0; ntl < 4; ntl++)
                bf_[ntl] = *(const bf16x8*)(&Bs[((ks * 8 + np * 4 + ntl) * 64 + l) * 8]);
#pragma unroll
            for (int mt = 0; mt < 4; mt++)
#pragma unroll
                for (int ntl = 0; ntl < 4; ntl++)
                    acc[mt][ntl] = __builtin_amdgcn_mfma_f32_16x16x32_bf16(af[mt][ks], bf_[ntl], acc[mt][ntl], 0, 0, 0);
        }
#pragma unroll
        for (int mt = 0; mt < 4; mt++)
#pragma unroll
            for (int ntl = 0; ntl < 4; ntl++) {
                int p = (np * 4 + ntl) * 16 + c15;
#pragma unroll
                for (int jr = 0; jr < 4; jr++) {
                    int cch = wv * 64 + mt * 16 + 4 * g + jr;
                    size_t base = ((size_t)b * Cc + cch) * HWn + hw0 + p;
                    float y = acc[mt][ntl][jr] + ws[P_OB + cch] + feat[base];
                    out[base] = y >= 0.f ? y : alpha * y;
                }
            }
    }
}

extern "C" void kernel_launch(void* const* d_in, const int* in_sizes, int n_in,
                              void* d_out, int out_size, void* d_ws, size_t ws_size,
                              hipStream_t stream) {
    InPtrs ip;
    for (int i = 0; i < 40; i++) ip.p[i] = (const float*)d_in[i];
    float* ws = (float*)d_ws;
    const float* feat = (const float*)d_in[0];
    float* out = (float*)d_out;

    k_prep<<<304, 256, 0, stream>>>(ip, ws);
    k_vpad<<<1280, 64, 0, stream>>>(ws);
    (void)hipFuncSetAttribute(reinterpret_cast<const void*>(k_qkv),
                              hipFuncAttributeMaxDynamicSharedMemorySize, 65536);
    k_qkv<<<800, 256, 65536, stream>>>(feat, ws);
    k_dconv<<<dim3(80, 8, 3), 256, 0, stream>>>(ws);
    k_tfrag<<<dim3(40, 8, 3), 256, 0, stream>>>(ws);
    (void)hipFuncSetAttribute(reinterpret_cast<const void*>(k_att),
                              hipFuncAttributeMaxDynamicSharedMemorySize, 51200);
    k_att<<<1280, 320, 51200, stream>>>(ws);
    k_out<<<1600, 256, 0, stream>>>(feat, ws, out);
}